// Round 11
// baseline (1600.115 us; speedup 1.0000x reference)
//
#include <hip/hip_runtime.h>
#include <stdint.h>

typedef __attribute__((ext_vector_type(8))) short s16x8;
typedef __attribute__((ext_vector_type(4))) float f32x4;

static __device__ __forceinline__ unsigned short f2bf(float f) {
  unsigned u = __float_as_uint(f);
  u += 0x7FFFu + ((u >> 16) & 1u);
  return (unsigned short)(u >> 16);
}
static __device__ __forceinline__ float bf2f(unsigned short h) {
  return __uint_as_float(((unsigned)h) << 16);
}
static __device__ __forceinline__ void sum8(uint4 u, float& a, float& q) {
  unsigned w[4] = {u.x, u.y, u.z, u.w};
#pragma unroll
  for (int i = 0; i < 4; ++i) {
    float v0 = __uint_as_float((w[i] & 0xFFFFu) << 16);
    float v1 = __uint_as_float(w[i] & 0xFFFF0000u);
    a += v0 + v1;
    q += v0 * v0 + v1 * v1;
  }
}

// ---------------- fused weight prep (all transposes/packs in ONE launch) ----------------
__global__ void k_prep(const float* __restrict__ W_tc, const float* __restrict__ W_val,
                       const float* __restrict__ W_off, const float* __restrict__ W_att,
                       const float* __restrict__ W_out, const float* __restrict__ W_ff1,
                       const float* __restrict__ W_ff2, const float* __restrict__ deconv_w,
                       const float* __restrict__ conv3_w,
                       unsigned short* __restrict__ Wt_tc, unsigned short* __restrict__ Wt_val,
                       unsigned short* __restrict__ Wt_oa, unsigned short* __restrict__ Wt_out,
                       unsigned short* __restrict__ Wt_ff1, unsigned short* __restrict__ Wt_ff2,
                       unsigned short* __restrict__ Wt_dc, unsigned short* __restrict__ wc3) {
  int idx = blockIdx.x * 256 + threadIdx.x;
  if (idx < 196608) { Wt_tc[idx] = f2bf(W_tc[idx]); return; }   // already [N=256][K=768]
  idx -= 196608;
  if (idx < 196608) {  // W_val [3][256][256] -> [l][n][k]
    int l = idx / 65536, r = idx - l * 65536, k = r >> 8, n = r & 255;
    Wt_val[l * 65536 + n * 256 + k] = f2bf(W_val[l * 65536 + r]);
    return;
  }
  idx -= 196608;
  if (idx < 147456) {  // W_off [3][256][192]
    int l = idx / 49152, r = idx - l * 49152, k = r / 192, n = r - k * 192;
    Wt_oa[l * 73728 + n * 256 + k] = f2bf(W_off[l * 49152 + r]);
    return;
  }
  idx -= 147456;
  if (idx < 73728) {   // W_att [3][256][96]
    int l = idx / 24576, r = idx - l * 24576, k = r / 96, n = r - k * 96;
    Wt_oa[l * 73728 + 192 * 256 + n * 256 + k] = f2bf(W_att[l * 24576 + r]);
    return;
  }
  idx -= 73728;
  if (idx < 196608) {  // W_out [3][256][256]
    int l = idx / 65536, r = idx - l * 65536, k = r >> 8, n = r & 255;
    Wt_out[l * 65536 + n * 256 + k] = f2bf(W_out[l * 65536 + r]);
    return;
  }
  idx -= 196608;
  if (idx < 393216) {  // W_ff1 [3][256][512]
    int l = idx / 131072, r = idx - l * 131072, k = r >> 9, n = r & 511;
    Wt_ff1[l * 131072 + n * 256 + k] = f2bf(W_ff1[l * 131072 + r]);
    return;
  }
  idx -= 393216;
  if (idx < 393216) {  // W_ff2 [3][512][256]
    int l = idx / 131072, r = idx - l * 131072, k = r >> 8, n = r & 255;
    Wt_ff2[l * 131072 + n * 512 + k] = f2bf(W_ff2[l * 131072 + r]);
    return;
  }
  idx -= 393216;
  if (idx < 524288) {  // deconv_w [oc][ic][8] -> [(tap*256+oc)][ic]
    int n = idx >> 8, k = idx & 255;
    Wt_dc[idx] = f2bf(deconv_w[(size_t)(n & 255) * 2048 + k * 8 + (n >> 8)]);
    return;
  }
  idx -= 524288;
  if (idx < 1327104) {  // conv3 per-fragment pack
    int tap = idx / 49152;
    int rem = idx - tap * 49152;
    int oc = rem >> 8, ic = rem & 255;
    int chunk = ic >> 5, kg = (ic >> 3) & 3, j = ic & 7;
    int ocblk = oc >> 4, lo = oc & 15;
    size_t frag = (size_t)(tap * 8 + chunk) * 12 + ocblk;
    wc3[(frag * 64 + kg * 16 + lo) * 8 + j] = f2bf(conv3_w[(oc * 256 + ic) * 27 + tap]);
    return;
  }
}

__global__ void k_cvt(const float* __restrict__ in, unsigned short* __restrict__ out, int n) {
  int i = blockIdx.x * 256 + threadIdx.x;
  if (i < n) out[i] = f2bf(in[i]);
}

// ---------------- restore: writes cam_x output (f32) AND bf16 GEMM-A layout ----------------
__global__ void k_restore2(const float* __restrict__ cx, const int* __restrict__ ids,
                           const float* __restrict__ mtok, float* __restrict__ out_camx,
                           unsigned short* __restrict__ camxT) {
  int idx = blockIdx.x * 256 + threadIdx.x;      // 811008, ch fastest
  if (idx >= 811008) return;
  int ch = idx % 768;
  int row = idx / 768;                           // c*176 + p
  int c = row / 176, p = row - c * 176;
  int id = ids[c * 176 + p];
  float v = (id < 44) ? cx[((size_t)(c * 44 + id)) * 768 + ch] : mtok[ch];
  camxT[idx] = f2bf(v);
  out_camx[((size_t)(c * 768 + ch)) * 176 + p] = v;
}

// ---------------- bf16 MFMA GEMM, B pre-transposed [N][K] bf16 ----------------
// MODE 0: f32 out Cf; MODE 2: bf16 out Cb; MODE 4: bf16 out + camera/level embeds
template <int MODE>
__global__ __launch_bounds__(256) void k_gemm(
    const unsigned short* __restrict__ A, int M, int lda,
    const unsigned short* __restrict__ Bt, int K, int N,
    const float* __restrict__ bias, const float* __restrict__ bias2, int n1, int relu,
    float* __restrict__ Cf, unsigned short* __restrict__ Cb, int ldc,
    const float* __restrict__ cemb, const float* __restrict__ lemb) {
  __shared__ short sA[128 * 40];
  const int t = threadIdx.x;
  const int l = t & 63, w = t >> 6;
  const int lo = l & 15, kg = l >> 4;
  const int row0 = blockIdx.x * 128, n0 = blockIdx.y * 64;
  const s16x8 bz = {0, 0, 0, 0, 0, 0, 0, 0};
  f32x4 acc[2][4] = {};
  s16x8 bc[4], bn[4];
#pragma unroll
  for (int nb = 0; nb < 4; ++nb) {
    int n = n0 + nb * 16 + lo;
    bc[nb] = (n < N) ? *(const s16x8*)&Bt[(size_t)n * K + kg * 8] : bz;
  }
  const int stR = t >> 1, stH = t & 1;
  for (int kc = 0; kc < K; kc += 32) {
    const bool pf = (kc + 32 < K);
    if (pf) {
#pragma unroll
      for (int nb = 0; nb < 4; ++nb) {
        int n = n0 + nb * 16 + lo;
        bn[nb] = (n < N) ? *(const s16x8*)&Bt[(size_t)n * K + kc + 32 + kg * 8] : bz;
      }
    }
    __syncthreads();
    {
      int r = row0 + stR;
      uint4 v0 = {0u, 0u, 0u, 0u}, v1 = {0u, 0u, 0u, 0u};
      if (r < M) {
        const unsigned short* src = A + (size_t)r * lda + kc + stH * 16;
        v0 = *(const uint4*)src;
        v1 = *(const uint4*)(src + 8);
      }
      *(uint4*)&sA[stR * 40 + stH * 16] = v0;
      *(uint4*)&sA[stR * 40 + stH * 16 + 8] = v1;
    }
    __syncthreads();
    s16x8 a0 = *(const s16x8*)&sA[(w * 32 + lo) * 40 + kg * 8];
    s16x8 a1 = *(const s16x8*)&sA[(w * 32 + 16 + lo) * 40 + kg * 8];
#pragma unroll
    for (int nb = 0; nb < 4; ++nb) {
      acc[0][nb] = __builtin_amdgcn_mfma_f32_16x16x32_bf16(a0, bc[nb], acc[0][nb], 0, 0, 0);
      acc[1][nb] = __builtin_amdgcn_mfma_f32_16x16x32_bf16(a1, bc[nb], acc[1][nb], 0, 0, 0);
    }
    if (pf) {
#pragma unroll
      for (int nb = 0; nb < 4; ++nb) bc[nb] = bn[nb];
    }
  }
#pragma unroll
  for (int m = 0; m < 2; ++m)
#pragma unroll
    for (int nb = 0; nb < 4; ++nb)
#pragma unroll
      for (int r = 0; r < 4; ++r) {
        int row = row0 + w * 32 + m * 16 + (kg << 2) + r;
        int col = n0 + nb * 16 + lo;
        if (row < M && col < N) {
          float v = acc[m][nb][r];
          if (bias) v += (col < n1) ? bias[col] : bias2[col - n1];
          if (relu) v = fmaxf(v, 0.f);
          if (MODE == 0) {
            Cf[(size_t)row * ldc + col] = v;
          } else if (MODE == 2) {
            Cb[(size_t)row * ldc + col] = f2bf(v);
          } else {  // MODE 4: vf epilogue — add camera + level embeds
            v += cemb[(row / 176) * 256 + col] + lemb[col];
            Cb[(size_t)row * ldc + col] = f2bf(v);
          }
        }
      }
}

// ---------------- fused GEMM (N=256) + bias + residual + LayerNorm ----------------
// Block: 64 rows x 256 cols; wave w owns rows w*16..w*16+15 (full rows -> in-block LN).
// qout = LN(qin + A@Bt^T + bias) ; also writes bf16 mirror qbout.
template <int KT>
__global__ __launch_bounds__(256) void k_gemmln(
    const unsigned short* __restrict__ A, int M,
    const unsigned short* __restrict__ Bt,
    const float* __restrict__ bias,
    const float* __restrict__ qin,
    const float* __restrict__ g, const float* __restrict__ b,
    float* __restrict__ qout, unsigned short* __restrict__ qbout) {
  __shared__ short sA[64 * (KT + 8)];
  const int t = threadIdx.x;
  const int l = t & 63, w = t >> 6;
  const int lo = l & 15, kg = l >> 4;
  const int row0 = blockIdx.x * 64;
  f32x4 acc[16] = {};
  // stage A[64][KT] (row-pad +8 elems -> 2-way-free ds_read)
#pragma unroll
  for (int i = 0; i < KT / 32; ++i) {
    int gr = t + i * 256;                 // granule: row = gr/(KT/8), col8 = gr%(KT/8)
    int row = gr / (KT / 8), c8 = gr - row * (KT / 8);
    int r = row0 + row;
    uint4 v = {0u, 0u, 0u, 0u};
    if (r < M) v = *(const uint4*)&A[(size_t)r * KT + c8 * 8];
    *(uint4*)&sA[row * (KT + 8) + c8 * 8] = v;
  }
  __syncthreads();
  const int arow = (w * 16 + lo) * (KT + 8);
#pragma unroll
  for (int h = 0; h < 2; ++h) {
    s16x8 bc[8], bn[8];
#pragma unroll
    for (int nb = 0; nb < 8; ++nb)
      bc[nb] = *(const s16x8*)&Bt[(size_t)(h * 128 + nb * 16 + lo) * KT + kg * 8];
#pragma unroll
    for (int kc = 0; kc < KT; kc += 32) {
      const bool pf = (kc + 32 < KT);
      if (pf) {
#pragma unroll
        for (int nb = 0; nb < 8; ++nb)
          bn[nb] = *(const s16x8*)&Bt[(size_t)(h * 128 + nb * 16 + lo) * KT + kc + 32 + kg * 8];
      }
      s16x8 a = *(const s16x8*)&sA[arow + kc + kg * 8];
#pragma unroll
      for (int nb = 0; nb < 8; ++nb)
        acc[h * 8 + nb] = __builtin_amdgcn_mfma_f32_16x16x32_bf16(a, bc[nb], acc[h * 8 + nb], 0, 0, 0);
      if (pf) {
#pragma unroll
        for (int nb = 0; nb < 8; ++nb) bc[nb] = bn[nb];
      }
    }
  }
  // epilogue: x = acc + bias + qin ; per-row LN via 16-lane shfl reduce
  float s1[4] = {0.f, 0.f, 0.f, 0.f}, s2[4] = {0.f, 0.f, 0.f, 0.f};
#pragma unroll
  for (int h = 0; h < 2; ++h)
#pragma unroll
    for (int nb = 0; nb < 8; ++nb) {
      int col = h * 128 + nb * 16 + lo;
      float bs = bias[col];
#pragma unroll
      for (int r = 0; r < 4; ++r) {
        int row = row0 + w * 16 + (kg << 2) + r;
        float v = acc[h * 8 + nb][r] + bs;
        if (row < M) v += qin[(size_t)row * 256 + col];
        acc[h * 8 + nb][r] = v;
        s1[r] += v;
        s2[r] += v * v;
      }
    }
#pragma unroll
  for (int o = 8; o >= 1; o >>= 1)
#pragma unroll
    for (int r = 0; r < 4; ++r) {
      s1[r] += __shfl_xor(s1[r], o, 64);
      s2[r] += __shfl_xor(s2[r], o, 64);
    }
  float mean[4], rstd[4];
#pragma unroll
  for (int r = 0; r < 4; ++r) {
    mean[r] = s1[r] * (1.0f / 256.0f);
    float var = s2[r] * (1.0f / 256.0f) - mean[r] * mean[r];
    rstd[r] = rsqrtf(var + 1e-5f);
  }
#pragma unroll
  for (int h = 0; h < 2; ++h)
#pragma unroll
    for (int nb = 0; nb < 8; ++nb) {
      int col = h * 128 + nb * 16 + lo;
      float gg = g[col], bb = b[col];
#pragma unroll
      for (int r = 0; r < 4; ++r) {
        int row = row0 + w * 16 + (kg << 2) + r;
        if (row < M) {
          float y = (acc[h * 8 + nb][r] - mean[r]) * rstd[r] * gg + bb;
          qout[(size_t)row * 256 + col] = y;
          qbout[(size_t)row * 256 + col] = f2bf(y);
        }
      }
    }
}

// ---------------- deconv: A staged ONCE in 64KB LDS, all 32 col-tiles in-kernel ----------------
__global__ __launch_bounds__(256, 2) void k_deconv(const unsigned short* __restrict__ A,
                                                   const unsigned short* __restrict__ Bt,
                                                   unsigned short* __restrict__ Cb, int M) {
  __shared__ short sA[128 * 256];   // 64 KB, XOR-swizzled granules
  const int t = threadIdx.x;
  const int l = t & 63, w = t >> 6;
  const int lo = l & 15, kg = l >> 4;
  const int row0 = blockIdx.x * 128;
#pragma unroll
  for (int i = 0; i < 16; ++i) {    // 4096 granules of 16B
    int g = t + i * 256;
    int row = g >> 5, gcol = g & 31;
    int r = row0 + row;
    uint4 v = {0u, 0u, 0u, 0u};
    if (r < M) v = *(const uint4*)&A[(size_t)r * 256 + gcol * 8];
    *(uint4*)&sA[row * 256 + ((gcol ^ (row & 7)) << 3)] = v;
  }
  __syncthreads();
  const int r0 = w * 32 + lo, r1 = r0 + 16;
  for (int nt = 0; nt < 32; ++nt) {
    f32x4 acc[2][4] = {};
    s16x8 bc[4], bn[4];
    const int ncol0 = nt * 64;
#pragma unroll
    for (int nb = 0; nb < 4; ++nb)
      bc[nb] = *(const s16x8*)&Bt[(size_t)(ncol0 + nb * 16 + lo) * 256 + kg * 8];
#pragma unroll
    for (int kc = 0; kc < 8; ++kc) {
      const bool pf = kc < 7;
      if (pf) {
#pragma unroll
        for (int nb = 0; nb < 4; ++nb)
          bn[nb] = *(const s16x8*)&Bt[(size_t)(ncol0 + nb * 16 + lo) * 256 + (kc + 1) * 32 + kg * 8];
      }
      int g0 = kc * 4 + kg;
      s16x8 a0 = *(const s16x8*)&sA[r0 * 256 + ((g0 ^ (r0 & 7)) << 3)];
      s16x8 a1 = *(const s16x8*)&sA[r1 * 256 + ((g0 ^ (r1 & 7)) << 3)];
#pragma unroll
      for (int nb = 0; nb < 4; ++nb) {
        acc[0][nb] = __builtin_amdgcn_mfma_f32_16x16x32_bf16(a0, bc[nb], acc[0][nb], 0, 0, 0);
        acc[1][nb] = __builtin_amdgcn_mfma_f32_16x16x32_bf16(a1, bc[nb], acc[1][nb], 0, 0, 0);
      }
      if (pf) {
#pragma unroll
        for (int nb = 0; nb < 4; ++nb) bc[nb] = bn[nb];
      }
    }
    const int tap = nt >> 2;
    const int t1 = tap >> 2, t2 = (tap >> 1) & 1, t3 = tap & 1;
#pragma unroll
    for (int m = 0; m < 2; ++m)
#pragma unroll
      for (int nb = 0; nb < 4; ++nb)
#pragma unroll
        for (int r = 0; r < 4; ++r) {
          int row = row0 + w * 32 + m * 16 + (kg << 2) + r;
          if (row < M) {
            int oc = (nt & 3) * 64 + nb * 16 + lo;
            int z = row / 2500, rr = row - z * 2500;
            int hy = rr / 50, wx = rr - hy * 50;
            int od = 2 * wx + 1 - t1, oh = 2 * hy + 1 - t2, ow = 2 * z + 1 - t3;
            Cb[((size_t)((od * 100 + oh) * 16 + ow)) * 256 + oc] = f2bf(acc[m][nb][r]);
          }
        }
  }
}

// ---------------- softmax + bilinear sampling + aggregate, 8 queries/block ----------------
__global__ __launch_bounds__(256) void k_sample(const float* __restrict__ oa,
                                                const float* __restrict__ val,
                                                unsigned short* __restrict__ aggb) {
  __shared__ float sl[96], sw[96];
  int t = threadIdx.x;
  int h = t >> 5, d = t & 31;
  const float* vbh0 = val + (size_t)h * 32 + d;
  for (int r = 0; r < 8; ++r) {
    int n = blockIdx.x * 8 + r;
    if (t < 96) sl[t] = oa[(size_t)n * 288 + 192 + t];
    __syncthreads();
    if (t < 96) {
      int hh = t / 12;
      float mx = -1e30f;
#pragma unroll
      for (int j = 0; j < 12; ++j) mx = fmaxf(mx, sl[hh * 12 + j]);
      sw[t] = __expf(sl[t] - mx);
    }
    __syncthreads();
    float ssum = 0.f;
#pragma unroll
    for (int j = 0; j < 12; ++j) ssum += sw[h * 12 + j];
    float inv = 1.f / ssum;
    float xr = ((float)(n % 50) + 0.5f) * (22.0f / 50.0f) - 0.5f;
    float yr = ((float)((n / 50) % 50) + 0.5f) * (8.0f / 50.0f) - 0.5f;
    float acc = 0.f;
    const float* offn = oa + (size_t)n * 288 + h * 24;
#pragma unroll
    for (int c = 0; c < 6; ++c)
#pragma unroll
      for (int p2 = 0; p2 < 2; ++p2) {
        float x = xr + offn[(c * 2 + p2) * 2];
        float y = yr + offn[(c * 2 + p2) * 2 + 1];
        float x0 = floorf(x), y0 = floorf(y);
        float wx = x - x0, wy = y - y0;
        int ix0 = min(max((int)x0, 0), 21), ix1 = min(max((int)x0 + 1, 0), 21);
        int iy0 = min(max((int)y0, 0), 7), iy1 = min(max((int)y0 + 1, 0), 7);
        const float* vb = vbh0 + (size_t)c * 176 * 768;
        float v00 = vb[(size_t)(iy0 * 22 + ix0) * 768];
        float v01 = vb[(size_t)(iy0 * 22 + ix1) * 768];
        float v10 = vb[(size_t)(iy1 * 22 + ix0) * 768];
        float v11 = vb[(size_t)(iy1 * 22 + ix1) * 768];
        float bil = (1.f - wx) * (1.f - wy) * v00 + wx * (1.f - wy) * v01 +
                    (1.f - wx) * wy * v10 + wx * wy * v11;
        acc += sw[h * 12 + c * 2 + p2] * inv * bil;
      }
    aggb[(size_t)n * 256 + t] = f2bf(acc);
    __syncthreads();
  }
}

// ---------------- GroupNorm 1 (256 ch, 16 groups) ----------------
__global__ __launch_bounds__(256) void k_gnstat1(const unsigned short* __restrict__ X, float* __restrict__ part) {
  __shared__ float s1[256], s2[256];
  int b = blockIdx.x, t = threadIdx.x;
  int oc8 = t & 31, v0 = t >> 5;
  float a = 0.f, q = 0.f;
#pragma unroll
  for (int i = 0; i < 8; ++i) {
    int vox = v0 + i * 8;
    uint4 u = *(const uint4*)&X[(size_t)b * 16384 + vox * 256 + oc8 * 8];
    sum8(u, a, q);
  }
  s1[t] = a; s2[t] = q;
  __syncthreads();
  if (t < 128) { s1[t] += s1[t + 128]; s2[t] += s2[t + 128]; }
  __syncthreads();
  if (t < 64) { s1[t] += s1[t + 64]; s2[t] += s2[t + 64]; }
  __syncthreads();
  if (t < 32) { s1[t] += s1[t + 32]; s2[t] += s2[t + 32]; }
  __syncthreads();
  if (t < 16) {
    part[t * 2500 + b] = s1[2 * t] + s1[2 * t + 1];
    part[40000 + t * 2500 + b] = s2[2 * t] + s2[2 * t + 1];
  }
}

__global__ __launch_bounds__(256) void k_gnred1(const float* __restrict__ part, float* __restrict__ gmv) {
  __shared__ float s1[256], s2[256];
  int g = blockIdx.x, t = threadIdx.x;
  float a = 0.f, q = 0.f;
  for (int i = t; i < 2500; i += 256) { a += part[g * 2500 + i]; q += part[40000 + g * 2500 + i]; }
  s1[t] = a; s2[t] = q;
  __syncthreads();
  for (int s = 128; s > 0; s >>= 1) {
    if (t < s) { s1[t] += s1[t + s]; s2[t] += s2[t + s]; }
    __syncthreads();
  }
  if (t == 0) {
    float m = s1[0] / 2560000.0f;
    float v = s2[0] / 2560000.0f - m * m;
    gmv[2 * g] = m; gmv[2 * g + 1] = rsqrtf(v + 1e-5f);
  }
}

__global__ __launch_bounds__(256) void k_gnapply1(unsigned short* __restrict__ X, const float* __restrict__ gmv,
                                                  const float* __restrict__ g, const float* __restrict__ b) {
  for (unsigned i = blockIdx.x * 256 + threadIdx.x; i < 5120000u; i += gridDim.x * 256) {
    unsigned e = i * 8u;
    int oc0 = e & 255, grp = oc0 >> 4;
    float mean = gmv[grp * 2], rstd = gmv[grp * 2 + 1];
    float4 g0 = *(const float4*)&g[oc0], g1 = *(const float4*)&g[oc0 + 4];
    float4 b0 = *(const float4*)&b[oc0], b1 = *(const float4*)&b[oc0 + 4];
    uint4 u = *(const uint4*)&X[e];
    unsigned w[4] = {u.x, u.y, u.z, u.w};
    float gg[8] = {g0.x, g0.y, g0.z, g0.w, g1.x, g1.y, g1.z, g1.w};
    float bb[8] = {b0.x, b0.y, b0.z, b0.w, b1.x, b1.y, b1.z, b1.w};
    unsigned o[4];
#pragma unroll
    for (int j = 0; j < 4; ++j) {
      float v0 = __uint_as_float((w[j] & 0xFFFFu) << 16);
      float v1 = __uint_as_float(w[j] & 0xFFFF0000u);
      v0 = fmaxf((v0 - mean) * rstd * gg[2 * j] + bb[2 * j], 0.f);
      v1 = fmaxf((v1 - mean) * rstd * gg[2 * j + 1] + bb[2 * j + 1], 0.f);
      o[j] = (unsigned)f2bf(v0) | ((unsigned)f2bf(v1) << 16);
    }
    *(uint4*)&X[e] = make_uint4(o[0], o[1], o[2], o[3]);
  }
}

// ---------------- conv3 3x3x3 (256->192): round-6 structure (measured best) ----------------
__global__ __launch_bounds__(256, 2) void k_conv3(const unsigned short* __restrict__ X,
                                                  const unsigned short* __restrict__ Wp,
                                                  unsigned short* __restrict__ Y) {
  __shared__ short sX[4 * 543 * 8];    // 34.75 KB
  int bid = blockIdx.x;
  int xcd = bid & 7, idx = bid >> 3;
  int swz = (xcd < 4 ? xcd * 163 : 652 + (xcd - 4) * 162) + idx;
  const int od = swz / 13;
  const int oh0 = (swz - od * 13) * 8;
  const int t = threadIdx.x;
  const int l = t & 63, w = t >> 6;
  const int kg = l >> 4, lo = l & 15;
  f32x4 acc[8][3] = {};
  s16x8 bc[9], bn[9];
  const unsigned short* Wl = Wp + (size_t)l * 8;
  const int w3 = w * 3;
#pragma unroll
  for (int t2 = 0; t2 < 3; ++t2)
#pragma unroll
    for (int nb = 0; nb < 3; ++nb)
      bc[t2 * 3 + nb] = *(const s16x8*)&Wl[(size_t)((t2 * 3 * 8) * 12 + w3 + nb) * 512];

  for (int gi = 0; gi < 72; ++gi) {
    const int chunk = gi / 9;
    const int sub = gi - chunk * 9;
    const int t1 = sub / 3, t3 = sub - t1 * 3;
    if (sub == 0) {
      __syncthreads();
#pragma unroll
      for (int i = 0; i < 9; ++i) {   // stage slab: 540 pos x 4 kgrp uint4
        int e = t + i * 256;
        if (e < 2160) {
          int pos = e >> 2, ks = e & 3;
          int sd = pos / 180, r2 = pos - sd * 180;
          int sh = r2 / 18, sw_ = r2 - sh * 18;
          int gd = od + sd - 1, gh = oh0 + sh - 1, gw = sw_ - 1;
          uint4 v = {0u, 0u, 0u, 0u};
          if ((unsigned)gd < 100u && (unsigned)gh < 100u && (unsigned)gw < 16u)
            v = *(const uint4*)&X[((size_t)((gd * 100 + gh) * 16 + gw)) * 256 + chunk * 32 + ks * 8];
          *(uint4*)&sX[(ks * 543 + pos) * 8] = v;
        }
      }
      __syncthreads();
    }
    const int gn1 = gi + 1;
    if (gn1 < 72) {
      const int c1 = gn1 / 9, su1 = gn1 - c1 * 9;
      const int t1n = su1 / 3, t3n = su1 - t1n * 3;
#pragma unroll
      for (int t2 = 0; t2 < 3; ++t2)
#pragma unroll
        for (int nb = 0; nb < 3; ++nb)
          bn[t2 * 3 + nb] = *(const s16x8*)&Wl[
              (size_t)(((t1n * 9 + t2 * 3 + t3n) * 8 + c1) * 12 + w3 + nb) * 512];
    }
    const int abase = kg * 543 + t1 * 180 + lo + t3;
#pragma unroll
    for (int sh = 0; sh < 10; ++sh) {
      s16x8 a = *(const s16x8*)&sX[(abase + sh * 18) * 8];
#pragma unroll
      for (int t2 = 0; t2 < 3; ++t2) {
        const int m = sh - t2;
        if (m >= 0 && m < 8) {
          acc[m][0] = __builtin_amdgcn_mfma_f32_16x16x32_bf16(a, bc[t2 * 3 + 0], acc[m][0], 0, 0, 0);
          acc[m][1] = __builtin_amdgcn_mfma_f32_16x16x32_bf16(a, bc[t2 * 3 + 1], acc[m][1], 0, 0, 0);
          acc[m][2] = __builtin_amdgcn_mfma_f32_16x16x32_bf16(a, bc[t2 * 3 + 2], acc[m][2], 0, 0, 0);
        }
      }
    }
#pragma unroll
    for (int i = 0; i < 9; ++i) bc[i] = bn[i];
  }
#pragma unroll
  for (int m = 0; m < 8; ++m) {
    int oh = oh0 + m;
    if (oh < 100) {
#pragma unroll
      for (int nb = 0; nb < 3; ++nb)
#pragma unroll
        for (int r = 0; r < 4; ++r) {
          int oc = w * 48 + nb * 16 + lo;
          int ow = (kg << 2) + r;
          Y[(size_t)oc * 160000 + (size_t)((od * 100 + oh) * 16) + ow] = f2bf(acc[m][nb][r]);
        }
    }
  }
}

// ---------------- GroupNorm 2 ----------------
__global__ __launch_bounds__(256) void k_gnstat2(const unsigned short* __restrict__ X, float* __restrict__ part) {
  __shared__ float s1[256], s2[256];
  int b = blockIdx.x, t = threadIdx.x;
  int ch = b / 10, pp = b - ch * 10;
  const unsigned short* base = X + (size_t)ch * 160000 + (size_t)pp * 16000;
  float a = 0.f, q = 0.f;
  for (int i = t; i < 2000; i += 256) {
    uint4 u = *(const uint4*)&base[i * 8];
    sum8(u, a, q);
  }
  s1[t] = a; s2[t] = q;
  __syncthreads();
  for (int s = 128; s > 0; s >>= 1) {
    if (t < s) { s1[t] += s1[t + s]; s2[t] += s2[t + s]; }
    __syncthreads();
  }
  if (t == 0) { part[80000 + ch * 10 + pp] = s1[0]; part[81920 + ch * 10 + pp] = s2[0]; }
}

__global__ __launch_bounds__(256) void k_gnred2(const float* __restrict__ part, float* __restrict__ gmv) {
  __shared__ float s1[256], s2[256];
  int g = blockIdx.x, t = threadIdx.x;
  float a = (t < 120) ? part[80000 + g * 120 + t] : 0.f;
  float q = (t < 120) ? part[81920 + g * 120 + t] : 0.f;
  s1[t] = a; s2[t] = q;
  __syncthreads();
  for (int s = 128; s > 0; s >>= 1) {
    if (t < s) { s1[t] += s1[t + s]; s2[t] += s2[t + s]; }
    __syncthreads();
  }
  if (t == 0) {
    float m = s1[0] / 1920000.0f;
    float v = s2[0] / 1920000.0f - m * m;
    gmv[2 * g] = m; gmv[2 * g + 1] = rsqrtf(v + 1e-5f);
  }
}

__global__ __launch_bounds__(256) void k_gnapply2(const unsigned short* __restrict__ X, const float* __restrict__ gmv,
                                                  const float* __restrict__ g, const float* __restrict__ b,
                                                  float* __restrict__ out) {
  for (unsigned i = blockIdx.x * 256 + threadIdx.x; i < 3840000u; i += gridDim.x * 256) {
    unsigned oc = i / 20000u;
    unsigned grp = oc / 12u;
    float mean = gmv[grp * 2], rstd = gmv[grp * 2 + 1];
    float gam = g[oc], bet = b[oc];
    unsigned e = i * 8u;
    uint4 u = *(const uint4*)&X[e];
    unsigned wv[4] = {u.x, u.y, u.z, u.w};
    float o[8];
#pragma unroll
    for (int j = 0; j < 4; ++j) {
      float v0 = __uint_as_float((wv[j] & 0xFFFFu) << 16);
      float v1 = __uint_as_float(wv[j] & 0xFFFF0000u);
      o[2 * j] = fmaxf((v0 - mean) * rstd * gam + bet, 0.f);
      o[2 * j + 1] = fmaxf((v1 - mean) * rstd * gam + bet, 0.f);
    }
    *(float4*)&out[e] = make_float4(o[0], o[1], o[2], o[3]);
    *(float4*)&out[e + 4] = make_float4(o[4], o[5], o[6], o[7]);
  }
}

// ---------------- host ----------------
static inline dim3 gemm_grid(int M, int N) { return dim3((M + 127) / 128, (N + 63) / 64); }

extern "C" void kernel_launch(void* const* d_in, const int* in_sizes, int n_in,
                              void* d_out, int out_size, void* d_ws, size_t ws_size,
                              hipStream_t stream) {
  const float* camera_x = (const float*)d_in[0];
  const int* ids = (const int*)d_in[1];
  const float* mask_tok = (const float*)d_in[4];
  const float* vol_emb = (const float*)d_in[5];
  const float* W_tc = (const float*)d_in[6];
  const float* b_tc = (const float*)d_in[7];
  const float* cams_emb = (const float*)d_in[8];
  const float* lvl_emb = (const float*)d_in[9];
  const float* W_off = (const float*)d_in[10];
  const float* b_off = (const float*)d_in[11];
  const float* W_att = (const float*)d_in[12];
  const float* b_att = (const float*)d_in[13];
  const float* W_val = (const float*)d_in[14];
  const float* b_val = (const float*)d_in[15];
  const float* W_out = (const float*)d_in[16];
  const float* b_out = (const float*)d_in[17];
  const float* ln1_g = (const float*)d_in[18];
  const float* ln1_b = (const float*)d_in[19];
  const float* W_ff1 = (const float*)d_in[20];
  const float* b_ff1 = (const float*)d_in[21];
  const float* W_ff2 = (const float*)d_in[22];
  const float* b_ff2 = (const float*)d_in[23];
  const float* ln2_g = (const float*)d_in[24];
  const float* ln2_b = (const float*)d_in[25];
  const float* deconv_w = (const float*)d_in[26];
  const float* gn1_g = (const float*)d_in[27];
  const float* gn1_b = (const float*)d_in[28];
  const float* conv3_w = (const float*)d_in[29];
  const float* gn2_g = (const float*)d_in[30];
  const float* gn2_b = (const float*)d_in[31];

  char* ws = (char*)d_ws;
  float* q             = (float*)(ws + 0);                      // 20.48 MB
  unsigned short* qb   = (unsigned short*)(ws + 20480000);      // 10.24 MB
  float* oa            = (float*)(ws + 51200000);               // 23.04 MB
  unsigned short* aggb = (unsigned short*)(ws + 74240000);      // 10.24 MB
  unsigned short* ffhb = (unsigned short*)(ws + 84480000);      // 20.48 MB
  float* val3          = (float*)(ws + 104960000);              // 3.24 MB [1056][768]
  unsigned short* featb= (unsigned short*)(ws + 108204032);     // 0.54 MB
  unsigned short* x1bf = (unsigned short*)(ws + 30720000);      // 81.92 MB (aliases decoder scratch)
  unsigned short* c3   = (unsigned short*)(ws + 112640000);     // 61.44 MB
  unsigned short* Wt_val = (unsigned short*)(ws + 174080000);
  unsigned short* Wt_oa  = (unsigned short*)(ws + 174473216);
  unsigned short* Wt_out = (unsigned short*)(ws + 174915584);
  unsigned short* Wt_ff1 = (unsigned short*)(ws + 175308800);
  unsigned short* Wt_ff2 = (unsigned short*)(ws + 176095232);
  unsigned short* Wt_dc  = (unsigned short*)(ws + 176881664);
  unsigned short* wc3    = (unsigned short*)(ws + 177930240);
  float* part = (float*)(ws + 180584448);
  float* gmv1 = (float*)(ws + 180920320);
  float* gmv2 = (float*)(ws + 180920448);
  unsigned short* Wt_tc  = (unsigned short*)(ws + 180920576);   // 393216 B
  unsigned short* camxT  = (unsigned short*)(ws + 181707008);   // 1622016 B

  float* out_x = (float*)d_out;
  float* out_camx = out_x + 30720000;

  // all weight prep in ONE launch (3,448,832 elements)
  k_prep<<<13472, 256, 0, stream>>>(W_tc, W_val, W_off, W_att, W_out, W_ff1, W_ff2,
                                    deconv_w, conv3_w,
                                    Wt_tc, Wt_val, Wt_oa, Wt_out, Wt_ff1, Wt_ff2, Wt_dc, wc3);

  k_restore2<<<3168, 256, 0, stream>>>(camera_x, ids, mask_tok, out_camx, camxT);
  // vf = relu(camxT @ W_tc^T + b_tc) + cams/level embeds (mode 4)
  k_gemm<4><<<gemm_grid(1056, 256), 256, 0, stream>>>(camxT, 1056, 768, Wt_tc, 768, 256,
                                                      b_tc, nullptr, 256, 1, nullptr, featb, 256,
                                                      cams_emb, lvl_emb);
  k_cvt<<<20000, 256, 0, stream>>>(vol_emb, qb, 5120000);

  // val for ALL 3 layers in one GEMM: [1056][768], bias = flat b_val
  k_gemm<0><<<gemm_grid(1056, 768), 256, 0, stream>>>(featb, 1056, 256, Wt_val, 256, 768,
                                                      b_val, nullptr, 768, 0, val3, nullptr, 768,
                                                      nullptr, nullptr);

  for (int lyr = 0; lyr < 3; ++lyr) {
    k_gemm<0><<<gemm_grid(20000, 288), 256, 0, stream>>>(qb, 20000, 256, Wt_oa + lyr * 73728, 256, 288,
                                                         b_off + lyr * 192, b_att + lyr * 96, 192, 0,
                                                         oa, nullptr, 288, nullptr, nullptr);
    k_sample<<<2500, 256, 0, stream>>>(oa, val3 + lyr * 256, aggb);
    // fused: q = LN(qres + aggb@W_out + b_out)   (layer 0 residual reads vol_emb directly)
    k_gemmln<256><<<313, 256, 0, stream>>>(aggb, 20000, Wt_out + lyr * 65536, b_out + lyr * 256,
                                           (lyr == 0) ? vol_emb : q,
                                           ln1_g + lyr * 256, ln1_b + lyr * 256, q, qb);
    k_gemm<2><<<gemm_grid(20000, 512), 256, 0, stream>>>(qb, 20000, 256, Wt_ff1 + lyr * 131072, 256, 512,
                                                         b_ff1 + lyr * 512, nullptr, 512, 1,
                                                         nullptr, ffhb, 512, nullptr, nullptr);
    // fused: q = LN(q + ffhb@W_ff2 + b_ff2)
    k_gemmln<512><<<313, 256, 0, stream>>>(ffhb, 20000, Wt_ff2 + lyr * 131072, b_ff2 + lyr * 256,
                                           q, ln2_g + lyr * 256, ln2_b + lyr * 256, q, qb);
  }

  // deconv: A staged once, all 8 taps in-kernel
  k_deconv<<<157, 256, 0, stream>>>(qb, Wt_dc, x1bf, 20000);

  k_gnstat1<<<2500, 256, 0, stream>>>(x1bf, part);
  k_gnred1<<<16, 256, 0, stream>>>(part, gmv1);
  k_gnapply1<<<2048, 256, 0, stream>>>(x1bf, gmv1, gn1_g, gn1_b);

  k_conv3<<<1300, 256, 0, stream>>>(x1bf, wc3, c3);

  k_gnstat2<<<1920, 256, 0, stream>>>(c3, part);
  k_gnred2<<<16, 256, 0, stream>>>(part, gmv2);
  k_gnapply2<<<2048, 256, 0, stream>>>(c3, gmv2, gn2_g, gn2_b, out_x);
}

// Round 12
// 1501.431 us; speedup vs baseline: 1.0657x; 1.0657x over previous
//
#include <hip/hip_runtime.h>
#include <stdint.h>

typedef __attribute__((ext_vector_type(8))) short s16x8;
typedef __attribute__((ext_vector_type(4))) float f32x4;

static __device__ __forceinline__ unsigned short f2bf(float f) {
  unsigned u = __float_as_uint(f);
  u += 0x7FFFu + ((u >> 16) & 1u);
  return (unsigned short)(u >> 16);
}
static __device__ __forceinline__ float bf2f(unsigned short h) {
  return __uint_as_float(((unsigned)h) << 16);
}

// ---------------- fused weight prep (all transposes/packs in ONE launch) ----------------
__global__ void k_prep(const float* __restrict__ W_tc, const float* __restrict__ W_val,
                       const float* __restrict__ W_off, const float* __restrict__ W_att,
                       const float* __restrict__ W_out, const float* __restrict__ W_ff1,
                       const float* __restrict__ W_ff2, const float* __restrict__ deconv_w,
                       const float* __restrict__ conv3_w,
                       unsigned short* __restrict__ Wt_tc, unsigned short* __restrict__ Wt_val,
                       unsigned short* __restrict__ Wt_oa, unsigned short* __restrict__ Wt_out,
                       unsigned short* __restrict__ Wt_ff1, unsigned short* __restrict__ Wt_ff2,
                       unsigned short* __restrict__ Wt_dc, unsigned short* __restrict__ wc3) {
  int idx = blockIdx.x * 256 + threadIdx.x;
  if (idx < 196608) { Wt_tc[idx] = f2bf(W_tc[idx]); return; }   // already [N=256][K=768]
  idx -= 196608;
  if (idx < 196608) {  // W_val [3][256][256] -> [l][n][k]
    int l = idx / 65536, r = idx - l * 65536, k = r >> 8, n = r & 255;
    Wt_val[l * 65536 + n * 256 + k] = f2bf(W_val[l * 65536 + r]);
    return;
  }
  idx -= 196608;
  if (idx < 147456) {  // W_off [3][256][192]
    int l = idx / 49152, r = idx - l * 49152, k = r / 192, n = r - k * 192;
    Wt_oa[l * 73728 + n * 256 + k] = f2bf(W_off[l * 49152 + r]);
    return;
  }
  idx -= 147456;
  if (idx < 73728) {   // W_att [3][256][96]
    int l = idx / 24576, r = idx - l * 24576, k = r / 96, n = r - k * 96;
    Wt_oa[l * 73728 + 192 * 256 + n * 256 + k] = f2bf(W_att[l * 24576 + r]);
    return;
  }
  idx -= 73728;
  if (idx < 196608) {  // W_out [3][256][256]
    int l = idx / 65536, r = idx - l * 65536, k = r >> 8, n = r & 255;
    Wt_out[l * 65536 + n * 256 + k] = f2bf(W_out[l * 65536 + r]);
    return;
  }
  idx -= 196608;
  if (idx < 393216) {  // W_ff1 [3][256][512]
    int l = idx / 131072, r = idx - l * 131072, k = r >> 9, n = r & 511;
    Wt_ff1[l * 131072 + n * 256 + k] = f2bf(W_ff1[l * 131072 + r]);
    return;
  }
  idx -= 393216;
  if (idx < 393216) {  // W_ff2 [3][512][256]
    int l = idx / 131072, r = idx - l * 131072, k = r >> 8, n = r & 255;
    Wt_ff2[l * 131072 + n * 512 + k] = f2bf(W_ff2[l * 131072 + r]);
    return;
  }
  idx -= 393216;
  if (idx < 524288) {  // deconv_w [oc][ic][8] -> [(tap*256+oc)][ic]
    int n = idx >> 8, k = idx & 255;
    Wt_dc[idx] = f2bf(deconv_w[(size_t)(n & 255) * 2048 + k * 8 + (n >> 8)]);
    return;
  }
  idx -= 524288;
  if (idx < 1327104) {  // conv3 per-fragment pack
    int tap = idx / 49152;
    int rem = idx - tap * 49152;
    int oc = rem >> 8, ic = rem & 255;
    int chunk = ic >> 5, kg = (ic >> 3) & 3, j = ic & 7;
    int ocblk = oc >> 4, lo = oc & 15;
    size_t frag = (size_t)(tap * 8 + chunk) * 12 + ocblk;
    wc3[(frag * 64 + kg * 16 + lo) * 8 + j] = f2bf(conv3_w[(oc * 256 + ic) * 27 + tap]);
    return;
  }
}

__global__ void k_cvt(const float* __restrict__ in, unsigned short* __restrict__ out, int n) {
  int i = blockIdx.x * 256 + threadIdx.x;
  if (i < n) out[i] = f2bf(in[i]);
}

__global__ void k_zero(float* __restrict__ p) { p[threadIdx.x] = 0.f; }  // 64 threads

// finalize GN stats: 16 threads, gmv[2g]=mean, gmv[2g+1]=rstd
__global__ void k_gnfin(const float* __restrict__ acc, float* __restrict__ gmv, float inv_n) {
  int t = threadIdx.x;
  float m = acc[2 * t] * inv_n;
  float v = acc[2 * t + 1] * inv_n - m * m;
  gmv[2 * t] = m;
  gmv[2 * t + 1] = rsqrtf(v + 1e-5f);
}

// ---------------- restore: writes cam_x output (f32) AND bf16 GEMM-A layout ----------------
__global__ void k_restore2(const float* __restrict__ cx, const int* __restrict__ ids,
                           const float* __restrict__ mtok, float* __restrict__ out_camx,
                           unsigned short* __restrict__ camxT) {
  int idx = blockIdx.x * 256 + threadIdx.x;      // 811008, ch fastest
  if (idx >= 811008) return;
  int ch = idx % 768;
  int row = idx / 768;                           // c*176 + p
  int c = row / 176, p = row - c * 176;
  int id = ids[c * 176 + p];
  float v = (id < 44) ? cx[((size_t)(c * 44 + id)) * 768 + ch] : mtok[ch];
  camxT[idx] = f2bf(v);
  out_camx[((size_t)(c * 768 + ch)) * 176 + p] = v;
}

// ---------------- bf16 MFMA GEMM, B pre-transposed [N][K] bf16 ----------------
// MODE 0: f32 out Cf; MODE 2: bf16 out Cb; MODE 4: bf16 out + camera/level embeds
template <int MODE>
__global__ __launch_bounds__(256) void k_gemm(
    const unsigned short* __restrict__ A, int M, int lda,
    const unsigned short* __restrict__ Bt, int K, int N,
    const float* __restrict__ bias, const float* __restrict__ bias2, int n1, int relu,
    float* __restrict__ Cf, unsigned short* __restrict__ Cb, int ldc,
    const float* __restrict__ cemb, const float* __restrict__ lemb) {
  __shared__ short sA[128 * 40];
  const int t = threadIdx.x;
  const int l = t & 63, w = t >> 6;
  const int lo = l & 15, kg = l >> 4;
  const int row0 = blockIdx.x * 128, n0 = blockIdx.y * 64;
  const s16x8 bz = {0, 0, 0, 0, 0, 0, 0, 0};
  f32x4 acc[2][4] = {};
  s16x8 bc[4], bn[4];
#pragma unroll
  for (int nb = 0; nb < 4; ++nb) {
    int n = n0 + nb * 16 + lo;
    bc[nb] = (n < N) ? *(const s16x8*)&Bt[(size_t)n * K + kg * 8] : bz;
  }
  const int stR = t >> 1, stH = t & 1;
  for (int kc = 0; kc < K; kc += 32) {
    const bool pf = (kc + 32 < K);
    if (pf) {
#pragma unroll
      for (int nb = 0; nb < 4; ++nb) {
        int n = n0 + nb * 16 + lo;
        bn[nb] = (n < N) ? *(const s16x8*)&Bt[(size_t)n * K + kc + 32 + kg * 8] : bz;
      }
    }
    __syncthreads();
    {
      int r = row0 + stR;
      uint4 v0 = {0u, 0u, 0u, 0u}, v1 = {0u, 0u, 0u, 0u};
      if (r < M) {
        const unsigned short* src = A + (size_t)r * lda + kc + stH * 16;
        v0 = *(const uint4*)src;
        v1 = *(const uint4*)(src + 8);
      }
      *(uint4*)&sA[stR * 40 + stH * 16] = v0;
      *(uint4*)&sA[stR * 40 + stH * 16 + 8] = v1;
    }
    __syncthreads();
    s16x8 a0 = *(const s16x8*)&sA[(w * 32 + lo) * 40 + kg * 8];
    s16x8 a1 = *(const s16x8*)&sA[(w * 32 + 16 + lo) * 40 + kg * 8];
#pragma unroll
    for (int nb = 0; nb < 4; ++nb) {
      acc[0][nb] = __builtin_amdgcn_mfma_f32_16x16x32_bf16(a0, bc[nb], acc[0][nb], 0, 0, 0);
      acc[1][nb] = __builtin_amdgcn_mfma_f32_16x16x32_bf16(a1, bc[nb], acc[1][nb], 0, 0, 0);
    }
    if (pf) {
#pragma unroll
      for (int nb = 0; nb < 4; ++nb) bc[nb] = bn[nb];
    }
  }
#pragma unroll
  for (int m = 0; m < 2; ++m)
#pragma unroll
    for (int nb = 0; nb < 4; ++nb)
#pragma unroll
      for (int r = 0; r < 4; ++r) {
        int row = row0 + w * 32 + m * 16 + (kg << 2) + r;
        int col = n0 + nb * 16 + lo;
        if (row < M && col < N) {
          float v = acc[m][nb][r];
          if (bias) v += (col < n1) ? bias[col] : bias2[col - n1];
          if (relu) v = fmaxf(v, 0.f);
          if (MODE == 0) {
            Cf[(size_t)row * ldc + col] = v;
          } else if (MODE == 2) {
            Cb[(size_t)row * ldc + col] = f2bf(v);
          } else {  // MODE 4: vf epilogue — add camera + level embeds
            v += cemb[(row / 176) * 256 + col] + lemb[col];
            Cb[(size_t)row * ldc + col] = f2bf(v);
          }
        }
      }
}

// ---------------- deconv: A staged ONCE in 64KB LDS + fused GN1 stats ----------------
__global__ __launch_bounds__(256, 2) void k_deconv(const unsigned short* __restrict__ A,
                                                   const unsigned short* __restrict__ Bt,
                                                   unsigned short* __restrict__ Cb, int M,
                                                   float* __restrict__ gnacc) {
  __shared__ short sA[128 * 256];   // 64 KB, XOR-swizzled granules
  const int t = threadIdx.x;
  const int l = t & 63, w = t >> 6;
  const int lo = l & 15, kg = l >> 4;
  const int row0 = blockIdx.x * 128;
#pragma unroll
  for (int i = 0; i < 16; ++i) {    // 4096 granules of 16B
    int g = t + i * 256;
    int row = g >> 5, gcol = g & 31;
    int r = row0 + row;
    uint4 v = {0u, 0u, 0u, 0u};
    if (r < M) v = *(const uint4*)&A[(size_t)r * 256 + gcol * 8];
    *(uint4*)&sA[row * 256 + ((gcol ^ (row & 7)) << 3)] = v;
  }
  __syncthreads();
  const int r0 = w * 32 + lo, r1 = r0 + 16;
  float gs1[16], gs2[16];
#pragma unroll
  for (int g = 0; g < 16; ++g) { gs1[g] = 0.f; gs2[g] = 0.f; }
  for (int ntH = 0; ntH < 8; ++ntH) {
#pragma unroll
    for (int ntL = 0; ntL < 4; ++ntL) {
      const int nt = ntH * 4 + ntL;
      f32x4 acc[2][4] = {};
      s16x8 bc[4], bn[4];
      const int ncol0 = nt * 64;
#pragma unroll
      for (int nb = 0; nb < 4; ++nb)
        bc[nb] = *(const s16x8*)&Bt[(size_t)(ncol0 + nb * 16 + lo) * 256 + kg * 8];
#pragma unroll
      for (int kc = 0; kc < 8; ++kc) {
        const bool pf = kc < 7;
        if (pf) {
#pragma unroll
          for (int nb = 0; nb < 4; ++nb)
            bn[nb] = *(const s16x8*)&Bt[(size_t)(ncol0 + nb * 16 + lo) * 256 + (kc + 1) * 32 + kg * 8];
        }
        int g0 = kc * 4 + kg;
        s16x8 a0 = *(const s16x8*)&sA[r0 * 256 + ((g0 ^ (r0 & 7)) << 3)];
        s16x8 a1 = *(const s16x8*)&sA[r1 * 256 + ((g0 ^ (r1 & 7)) << 3)];
#pragma unroll
        for (int nb = 0; nb < 4; ++nb) {
          acc[0][nb] = __builtin_amdgcn_mfma_f32_16x16x32_bf16(a0, bc[nb], acc[0][nb], 0, 0, 0);
          acc[1][nb] = __builtin_amdgcn_mfma_f32_16x16x32_bf16(a1, bc[nb], acc[1][nb], 0, 0, 0);
        }
        if (pf) {
#pragma unroll
          for (int nb = 0; nb < 4; ++nb) bc[nb] = bn[nb];
        }
      }
      const int t1 = ntH >> 2, t2 = (ntH >> 1) & 1, t3 = ntH & 1;
#pragma unroll
      for (int m = 0; m < 2; ++m)
#pragma unroll
        for (int nb = 0; nb < 4; ++nb)
#pragma unroll
          for (int r = 0; r < 4; ++r) {
            int row = row0 + w * 32 + m * 16 + (kg << 2) + r;
            float v = acc[m][nb][r];
            gs1[ntL * 4 + nb] += v;          // static index (rule #20)
            gs2[ntL * 4 + nb] += v * v;      // rows >= M contribute exact 0
            if (row < M) {
              int oc = ntL * 64 + nb * 16 + lo;
              int z = row / 2500, rr = row - z * 2500;
              int hy = rr / 50, wx = rr - hy * 50;
              int od = 2 * wx + 1 - t1, oh = 2 * hy + 1 - t2, ow = 2 * z + 1 - t3;
              Cb[((size_t)((od * 100 + oh) * 16 + ow)) * 256 + oc] = f2bf(v);
            }
          }
    }
  }
  // block reduce -> gnacc[0..31]
  __syncthreads();
  float* red = (float*)sA;
#pragma unroll
  for (int g = 0; g < 16; ++g) {
    float a = gs1[g], qq = gs2[g];
#pragma unroll
    for (int o = 32; o >= 1; o >>= 1) {
      a += __shfl_xor(a, o, 64);
      qq += __shfl_xor(qq, o, 64);
    }
    if (l == 0) { red[w * 32 + g * 2] = a; red[w * 32 + g * 2 + 1] = qq; }
  }
  __syncthreads();
  if (t < 32) atomicAdd(&gnacc[t], red[t] + red[32 + t] + red[64 + t] + red[96 + t]);
}

// ---------------- softmax + bilinear sampling + aggregate, 8 queries/block ----------------
__global__ __launch_bounds__(256) void k_sample(const float* __restrict__ oa,
                                                const float* __restrict__ val,
                                                unsigned short* __restrict__ aggb) {
  __shared__ float sl[96], sw[96];
  int t = threadIdx.x;
  int h = t >> 5, d = t & 31;
  const float* vbh0 = val + (size_t)h * 32 + d;
  for (int r = 0; r < 8; ++r) {
    int n = blockIdx.x * 8 + r;
    if (t < 96) sl[t] = oa[(size_t)n * 288 + 192 + t];
    __syncthreads();
    if (t < 96) {
      int hh = t / 12;
      float mx = -1e30f;
#pragma unroll
      for (int j = 0; j < 12; ++j) mx = fmaxf(mx, sl[hh * 12 + j]);
      sw[t] = __expf(sl[t] - mx);
    }
    __syncthreads();
    float ssum = 0.f;
#pragma unroll
    for (int j = 0; j < 12; ++j) ssum += sw[h * 12 + j];
    float inv = 1.f / ssum;
    float xr = ((float)(n % 50) + 0.5f) * (22.0f / 50.0f) - 0.5f;
    float yr = ((float)((n / 50) % 50) + 0.5f) * (8.0f / 50.0f) - 0.5f;
    float acc = 0.f;
    const float* offn = oa + (size_t)n * 288 + h * 24;
#pragma unroll
    for (int c = 0; c < 6; ++c)
#pragma unroll
      for (int p2 = 0; p2 < 2; ++p2) {
        float x = xr + offn[(c * 2 + p2) * 2];
        float y = yr + offn[(c * 2 + p2) * 2 + 1];
        float x0 = floorf(x), y0 = floorf(y);
        float wx = x - x0, wy = y - y0;
        int ix0 = min(max((int)x0, 0), 21), ix1 = min(max((int)x0 + 1, 0), 21);
        int iy0 = min(max((int)y0, 0), 7), iy1 = min(max((int)y0 + 1, 0), 7);
        const float* vb = vbh0 + (size_t)c * 176 * 768;
        float v00 = vb[(size_t)(iy0 * 22 + ix0) * 768];
        float v01 = vb[(size_t)(iy0 * 22 + ix1) * 768];
        float v10 = vb[(size_t)(iy1 * 22 + ix0) * 768];
        float v11 = vb[(size_t)(iy1 * 22 + ix1) * 768];
        float bil = (1.f - wx) * (1.f - wy) * v00 + wx * (1.f - wy) * v01 +
                    (1.f - wx) * wy * v10 + wx * wy * v11;
        acc += sw[h * 12 + c * 2 + p2] * inv * bil;
      }
    aggb[(size_t)n * 256 + t] = f2bf(acc);
    __syncthreads();
  }
}

// ---------------- residual + LayerNorm(256), 8 rows/block ----------------
__global__ __launch_bounds__(256) void k_addln(float* __restrict__ q, const float* __restrict__ p,
                                               const float* __restrict__ g, const float* __restrict__ b,
                                               unsigned short* __restrict__ qb) {
  __shared__ float red[8];
  int t = threadIdx.x;
  int w = t >> 6;
  float gg = g[t], bb = b[t];
  for (int r = 0; r < 8; ++r) {
    size_t n = (size_t)blockIdx.x * 8 + r;
    float x = q[n * 256 + t] + p[n * 256 + t];
    float s1 = x, s2 = x * x;
#pragma unroll
    for (int o = 32; o >= 1; o >>= 1) {
      s1 += __shfl_xor(s1, o, 64);
      s2 += __shfl_xor(s2, o, 64);
    }
    if ((t & 63) == 0) { red[w * 2] = s1; red[w * 2 + 1] = s2; }
    __syncthreads();
    s1 = red[0] + red[2] + red[4] + red[6];
    s2 = red[1] + red[3] + red[5] + red[7];
    float mean = s1 * (1.0f / 256.0f);
    float var = s2 * (1.0f / 256.0f) - mean * mean;
    float y = (x - mean) * rsqrtf(var + 1e-5f) * gg + bb;
    q[n * 256 + t] = y;
    qb[n * 256 + t] = f2bf(y);
    __syncthreads();
  }
}

// ---------------- GN1 apply (reads gmv1 from fused stats) ----------------
__global__ __launch_bounds__(256) void k_gnapply1(unsigned short* __restrict__ X, const float* __restrict__ gmv,
                                                  const float* __restrict__ g, const float* __restrict__ b) {
  for (unsigned i = blockIdx.x * 256 + threadIdx.x; i < 5120000u; i += gridDim.x * 256) {
    unsigned e = i * 8u;
    int oc0 = e & 255, grp = oc0 >> 4;
    float mean = gmv[grp * 2], rstd = gmv[grp * 2 + 1];
    float4 g0 = *(const float4*)&g[oc0], g1 = *(const float4*)&g[oc0 + 4];
    float4 b0 = *(const float4*)&b[oc0], b1 = *(const float4*)&b[oc0 + 4];
    uint4 u = *(const uint4*)&X[e];
    unsigned w[4] = {u.x, u.y, u.z, u.w};
    float gg[8] = {g0.x, g0.y, g0.z, g0.w, g1.x, g1.y, g1.z, g1.w};
    float bb[8] = {b0.x, b0.y, b0.z, b0.w, b1.x, b1.y, b1.z, b1.w};
    unsigned o[4];
#pragma unroll
    for (int j = 0; j < 4; ++j) {
      float v0 = __uint_as_float((w[j] & 0xFFFFu) << 16);
      float v1 = __uint_as_float(w[j] & 0xFFFF0000u);
      v0 = fmaxf((v0 - mean) * rstd * gg[2 * j] + bb[2 * j], 0.f);
      v1 = fmaxf((v1 - mean) * rstd * gg[2 * j + 1] + bb[2 * j + 1], 0.f);
      o[j] = (unsigned)f2bf(v0) | ((unsigned)f2bf(v1) << 16);
    }
    *(uint4*)&X[e] = make_uint4(o[0], o[1], o[2], o[3]);
  }
}

// ---------------- conv3 3x3x3 (256->192): round-6 structure + fused GN2 stats ----------------
__global__ __launch_bounds__(256, 2) void k_conv3(const unsigned short* __restrict__ X,
                                                  const unsigned short* __restrict__ Wp,
                                                  unsigned short* __restrict__ Y,
                                                  float* __restrict__ gnacc) {
  __shared__ short sX[4 * 543 * 8];    // 34.75 KB
  int bid = blockIdx.x;
  int xcd = bid & 7, idx = bid >> 3;
  int swz = (xcd < 4 ? xcd * 163 : 652 + (xcd - 4) * 162) + idx;
  const int od = swz / 13;
  const int oh0 = (swz - od * 13) * 8;
  const int t = threadIdx.x;
  const int l = t & 63, w = t >> 6;
  const int kg = l >> 4, lo = l & 15;
  f32x4 acc[8][3] = {};
  s16x8 bc[9], bn[9];
  const unsigned short* Wl = Wp + (size_t)l * 8;
  const int w3 = w * 3;
#pragma unroll
  for (int t2 = 0; t2 < 3; ++t2)
#pragma unroll
    for (int nb = 0; nb < 3; ++nb)
      bc[t2 * 3 + nb] = *(const s16x8*)&Wl[(size_t)((t2 * 3 * 8) * 12 + w3 + nb) * 512];

  for (int gi = 0; gi < 72; ++gi) {
    const int chunk = gi / 9;
    const int sub = gi - chunk * 9;
    const int t1 = sub / 3, t3 = sub - t1 * 3;
    if (sub == 0) {
      __syncthreads();
#pragma unroll
      for (int i = 0; i < 9; ++i) {   // stage slab: 540 pos x 4 kgrp uint4
        int e = t + i * 256;
        if (e < 2160) {
          int pos = e >> 2, ks = e & 3;
          int sd = pos / 180, r2 = pos - sd * 180;
          int sh = r2 / 18, sw_ = r2 - sh * 18;
          int gd = od + sd - 1, gh = oh0 + sh - 1, gw = sw_ - 1;
          uint4 v = {0u, 0u, 0u, 0u};
          if ((unsigned)gd < 100u && (unsigned)gh < 100u && (unsigned)gw < 16u)
            v = *(const uint4*)&X[((size_t)((gd * 100 + gh) * 16 + gw)) * 256 + chunk * 32 + ks * 8];
          *(uint4*)&sX[(ks * 543 + pos) * 8] = v;
        }
      }
      __syncthreads();
    }
    const int gn1 = gi + 1;
    if (gn1 < 72) {
      const int c1 = gn1 / 9, su1 = gn1 - c1 * 9;
      const int t1n = su1 / 3, t3n = su1 - t1n * 3;
#pragma unroll
      for (int t2 = 0; t2 < 3; ++t2)
#pragma unroll
        for (int nb = 0; nb < 3; ++nb)
          bn[t2 * 3 + nb] = *(const s16x8*)&Wl[
              (size_t)(((t1n * 9 + t2 * 3 + t3n) * 8 + c1) * 12 + w3 + nb) * 512];
    }
    const int abase = kg * 543 + t1 * 180 + lo + t3;
#pragma unroll
    for (int sh = 0; sh < 10; ++sh) {
      s16x8 a = *(const s16x8*)&sX[(abase + sh * 18) * 8];
#pragma unroll
      for (int t2 = 0; t2 < 3; ++t2) {
        const int m = sh - t2;
        if (m >= 0 && m < 8) {
          acc[m][0] = __builtin_amdgcn_mfma_f32_16x16x32_bf16(a, bc[t2 * 3 + 0], acc[m][0], 0, 0, 0);
          acc[m][1] = __builtin_amdgcn_mfma_f32_16x16x32_bf16(a, bc[t2 * 3 + 1], acc[m][1], 0, 0, 0);
          acc[m][2] = __builtin_amdgcn_mfma_f32_16x16x32_bf16(a, bc[t2 * 3 + 2], acc[m][2], 0, 0, 0);
        }
      }
    }
#pragma unroll
    for (int i = 0; i < 9; ++i) bc[i] = bn[i];
  }
  // epilogue: store + fused GN2 stats (guarded by oh<100)
  __syncthreads();                       // all waves done with sX -> reuse as bins
  float* lb = (float*)sX;
  if (t < 32) lb[t] = 0.f;
  __syncthreads();
  float cs1[3] = {0.f, 0.f, 0.f}, cs2[3] = {0.f, 0.f, 0.f};
#pragma unroll
  for (int m = 0; m < 8; ++m) {
    int oh = oh0 + m;
    if (oh < 100) {
#pragma unroll
      for (int nb = 0; nb < 3; ++nb)
#pragma unroll
        for (int r = 0; r < 4; ++r) {
          int oc = w * 48 + nb * 16 + lo;
          int ow = (kg << 2) + r;
          float v = acc[m][nb][r];
          cs1[nb] += v;
          cs2[nb] += v * v;
          Y[(size_t)oc * 160000 + (size_t)((od * 100 + oh) * 16) + ow] = f2bf(v);
        }
    }
  }
#pragma unroll
  for (int nb = 0; nb < 3; ++nb) {
    float a = cs1[nb], qq = cs2[nb];
    a += __shfl_xor(a, 16, 64); qq += __shfl_xor(qq, 16, 64);
    a += __shfl_xor(a, 32, 64); qq += __shfl_xor(qq, 32, 64);
    if (kg == 0) {
      int grp = (w * 48 + nb * 16 + lo) / 12;
      atomicAdd(&lb[grp * 2], a);
      atomicAdd(&lb[grp * 2 + 1], qq);
    }
  }
  __syncthreads();
  if (t < 32) atomicAdd(&gnacc[t], lb[t]);
}

// ---------------- GN2 apply (reads gmv2 from fused stats) ----------------
__global__ __launch_bounds__(256) void k_gnapply2(const unsigned short* __restrict__ X, const float* __restrict__ gmv,
                                                  const float* __restrict__ g, const float* __restrict__ b,
                                                  float* __restrict__ out) {
  for (unsigned i = blockIdx.x * 256 + threadIdx.x; i < 3840000u; i += gridDim.x * 256) {
    unsigned oc = i / 20000u;
    unsigned grp = oc / 12u;
    float mean = gmv[grp * 2], rstd = gmv[grp * 2 + 1];
    float gam = g[oc], bet = b[oc];
    unsigned e = i * 8u;
    uint4 u = *(const uint4*)&X[e];
    unsigned wv[4] = {u.x, u.y, u.z, u.w};
    float o[8];
#pragma unroll
    for (int j = 0; j < 4; ++j) {
      float v0 = __uint_as_float((wv[j] & 0xFFFFu) << 16);
      float v1 = __uint_as_float(wv[j] & 0xFFFF0000u);
      o[2 * j] = fmaxf((v0 - mean) * rstd * gam + bet, 0.f);
      o[2 * j + 1] = fmaxf((v1 - mean) * rstd * gam + bet, 0.f);
    }
    *(float4*)&out[e] = make_float4(o[0], o[1], o[2], o[3]);
    *(float4*)&out[e + 4] = make_float4(o[4], o[5], o[6], o[7]);
  }
}

// ---------------- host ----------------
static inline dim3 gemm_grid(int M, int N) { return dim3((M + 127) / 128, (N + 63) / 64); }

extern "C" void kernel_launch(void* const* d_in, const int* in_sizes, int n_in,
                              void* d_out, int out_size, void* d_ws, size_t ws_size,
                              hipStream_t stream) {
  const float* camera_x = (const float*)d_in[0];
  const int* ids = (const int*)d_in[1];
  const float* mask_tok = (const float*)d_in[4];
  const float* vol_emb = (const float*)d_in[5];
  const float* W_tc = (const float*)d_in[6];
  const float* b_tc = (const float*)d_in[7];
  const float* cams_emb = (const float*)d_in[8];
  const float* lvl_emb = (const float*)d_in[9];
  const float* W_off = (const float*)d_in[10];
  const float* b_off = (const float*)d_in[11];
  const float* W_att = (const float*)d_in[12];
  const float* b_att = (const float*)d_in[13];
  const float* W_val = (const float*)d_in[14];
  const float* b_val = (const float*)d_in[15];
  const float* W_out = (const float*)d_in[16];
  const float* b_out = (const float*)d_in[17];
  const float* ln1_g = (const float*)d_in[18];
  const float* ln1_b = (const float*)d_in[19];
  const float* W_ff1 = (const float*)d_in[20];
  const float* b_ff1 = (const float*)d_in[21];
  const float* W_ff2 = (const float*)d_in[22];
  const float* b_ff2 = (const float*)d_in[23];
  const float* ln2_g = (const float*)d_in[24];
  const float* ln2_b = (const float*)d_in[25];
  const float* deconv_w = (const float*)d_in[26];
  const float* gn1_g = (const float*)d_in[27];
  const float* gn1_b = (const float*)d_in[28];
  const float* conv3_w = (const float*)d_in[29];
  const float* gn2_g = (const float*)d_in[30];
  const float* gn2_b = (const float*)d_in[31];

  char* ws = (char*)d_ws;
  float* q             = (float*)(ws + 0);                      // 20.48 MB
  unsigned short* qb   = (unsigned short*)(ws + 20480000);      // 10.24 MB
  float* proj          = (float*)(ws + 30720000);               // 20.48 MB
  float* oa            = (float*)(ws + 51200000);               // 23.04 MB
  unsigned short* aggb = (unsigned short*)(ws + 74240000);      // 10.24 MB
  unsigned short* ffhb = (unsigned short*)(ws + 84480000);      // 20.48 MB
  float* val3          = (float*)(ws + 104960000);              // 3.24 MB [1056][768]
  unsigned short* featb= (unsigned short*)(ws + 108204032);     // 0.54 MB
  unsigned short* x1bf = (unsigned short*)(ws + 30720000);      // 81.92 MB (aliases decoder scratch)
  unsigned short* c3   = (unsigned short*)(ws + 112640000);     // 61.44 MB
  unsigned short* Wt_val = (unsigned short*)(ws + 174080000);
  unsigned short* Wt_oa  = (unsigned short*)(ws + 174473216);
  unsigned short* Wt_out = (unsigned short*)(ws + 174915584);
  unsigned short* Wt_ff1 = (unsigned short*)(ws + 175308800);
  unsigned short* Wt_ff2 = (unsigned short*)(ws + 176095232);
  unsigned short* Wt_dc  = (unsigned short*)(ws + 176881664);
  unsigned short* wc3    = (unsigned short*)(ws + 177930240);
  float* gmv1 = (float*)(ws + 180920320);
  float* gmv2 = (float*)(ws + 180920448);
  unsigned short* Wt_tc  = (unsigned short*)(ws + 180920576);   // 393216 B
  unsigned short* camxT  = (unsigned short*)(ws + 181707008);   // 1622016 B
  float* gnacc = (float*)(ws + 183329024);                      // 64 floats

  float* out_x = (float*)d_out;
  float* out_camx = out_x + 30720000;

  k_zero<<<1, 64, 0, stream>>>(gnacc);
  // all weight prep in ONE launch (3,448,832 elements)
  k_prep<<<13472, 256, 0, stream>>>(W_tc, W_val, W_off, W_att, W_out, W_ff1, W_ff2,
                                    deconv_w, conv3_w,
                                    Wt_tc, Wt_val, Wt_oa, Wt_out, Wt_ff1, Wt_ff2, Wt_dc, wc3);

  k_restore2<<<3168, 256, 0, stream>>>(camera_x, ids, mask_tok, out_camx, camxT);
  // vf = relu(camxT @ W_tc^T + b_tc) + cams/level embeds (mode 4)
  k_gemm<4><<<gemm_grid(1056, 256), 256, 0, stream>>>(camxT, 1056, 768, Wt_tc, 768, 256,
                                                      b_tc, nullptr, 256, 1, nullptr, featb, 256,
                                                      cams_emb, lvl_emb);
  hipMemcpyAsync(q, vol_emb, (size_t)20000 * 256 * 4, hipMemcpyDeviceToDevice, stream);
  k_cvt<<<20000, 256, 0, stream>>>(vol_emb, qb, 5120000);

  // val for ALL 3 layers in one GEMM: [1056][768], bias = flat b_val
  k_gemm<0><<<gemm_grid(1056, 768), 256, 0, stream>>>(featb, 1056, 256, Wt_val, 256, 768,
                                                      b_val, nullptr, 768, 0, val3, nullptr, 768,
                                                      nullptr, nullptr);

  for (int lyr = 0; lyr < 3; ++lyr) {
    k_gemm<0><<<gemm_grid(20000, 288), 256, 0, stream>>>(qb, 20000, 256, Wt_oa + lyr * 73728, 256, 288,
                                                         b_off + lyr * 192, b_att + lyr * 96, 192, 0,
                                                         oa, nullptr, 288, nullptr, nullptr);
    k_sample<<<2500, 256, 0, stream>>>(oa, val3 + lyr * 256, aggb);
    k_gemm<0><<<gemm_grid(20000, 256), 256, 0, stream>>>(aggb, 20000, 256, Wt_out + lyr * 65536, 256, 256,
                                                         b_out + lyr * 256, nullptr, 256, 0,
                                                         proj, nullptr, 256, nullptr, nullptr);
    k_addln<<<2500, 256, 0, stream>>>(q, proj, ln1_g + lyr * 256, ln1_b + lyr * 256, qb);
    k_gemm<2><<<gemm_grid(20000, 512), 256, 0, stream>>>(qb, 20000, 256, Wt_ff1 + lyr * 131072, 256, 512,
                                                         b_ff1 + lyr * 512, nullptr, 512, 1,
                                                         nullptr, ffhb, 512, nullptr, nullptr);
    k_gemm<0><<<gemm_grid(20000, 256), 256, 0, stream>>>(ffhb, 20000, 512, Wt_ff2 + lyr * 131072, 512, 256,
                                                         b_ff2 + lyr * 256, nullptr, 256, 0,
                                                         proj, nullptr, 256, nullptr, nullptr);
    k_addln<<<2500, 256, 0, stream>>>(q, proj, ln2_g + lyr * 256, ln2_b + lyr * 256, qb);
  }

  // deconv: A staged once, all 8 taps in-kernel, GN1 stats fused
  k_deconv<<<157, 256, 0, stream>>>(qb, Wt_dc, x1bf, 20000, gnacc);
  k_gnfin<<<1, 16, 0, stream>>>(gnacc, gmv1, 1.0f / 2560000.0f);
  k_gnapply1<<<2048, 256, 0, stream>>>(x1bf, gmv1, gn1_g, gn1_b);

  k_conv3<<<1300, 256, 0, stream>>>(x1bf, wc3, c3, gnacc + 32);
  k_gnfin<<<1, 16, 0, stream>>>(gnacc + 32, gmv2, 1.0f / 1920000.0f);
  k_gnapply2<<<2048, 256, 0, stream>>>(c3, gmv2, gn2_g, gn2_b, out_x);
}

// Round 13
// 1415.668 us; speedup vs baseline: 1.1303x; 1.0606x over previous
//
#include <hip/hip_runtime.h>
#include <stdint.h>

typedef __attribute__((ext_vector_type(8))) short s16x8;
typedef __attribute__((ext_vector_type(4))) float f32x4;

static __device__ __forceinline__ unsigned short f2bf(float f) {
  unsigned u = __float_as_uint(f);
  u += 0x7FFFu + ((u >> 16) & 1u);
  return (unsigned short)(u >> 16);
}
static __device__ __forceinline__ float bf2f(unsigned short h) {
  return __uint_as_float(((unsigned)h) << 16);
}
static __device__ __forceinline__ void sum8(uint4 u, float& a, float& q) {
  unsigned w[4] = {u.x, u.y, u.z, u.w};
#pragma unroll
  for (int i = 0; i < 4; ++i) {
    float v0 = __uint_as_float((w[i] & 0xFFFFu) << 16);
    float v1 = __uint_as_float(w[i] & 0xFFFF0000u);
    a += v0 + v1;
    q += v0 * v0 + v1 * v1;
  }
}

// ---------------- fused weight prep (all transposes/packs in ONE launch) ----------------
__global__ void k_prep(const float* __restrict__ W_tc, const float* __restrict__ W_val,
                       const float* __restrict__ W_off, const float* __restrict__ W_att,
                       const float* __restrict__ W_out, const float* __restrict__ W_ff1,
                       const float* __restrict__ W_ff2, const float* __restrict__ deconv_w,
                       const float* __restrict__ conv3_w,
                       unsigned short* __restrict__ Wt_tc, unsigned short* __restrict__ Wt_val,
                       unsigned short* __restrict__ Wt_oa, unsigned short* __restrict__ Wt_out,
                       unsigned short* __restrict__ Wt_ff1, unsigned short* __restrict__ Wt_ff2,
                       unsigned short* __restrict__ Wt_dc, unsigned short* __restrict__ wc3) {
  int idx = blockIdx.x * 256 + threadIdx.x;
  if (idx < 196608) { Wt_tc[idx] = f2bf(W_tc[idx]); return; }   // already [N=256][K=768]
  idx -= 196608;
  if (idx < 196608) {  // W_val [3][256][256] -> [l][n][k]
    int l = idx / 65536, r = idx - l * 65536, k = r >> 8, n = r & 255;
    Wt_val[l * 65536 + n * 256 + k] = f2bf(W_val[l * 65536 + r]);
    return;
  }
  idx -= 196608;
  if (idx < 147456) {  // W_off [3][256][192]
    int l = idx / 49152, r = idx - l * 49152, k = r / 192, n = r - k * 192;
    Wt_oa[l * 73728 + n * 256 + k] = f2bf(W_off[l * 49152 + r]);
    return;
  }
  idx -= 147456;
  if (idx < 73728) {   // W_att [3][256][96]
    int l = idx / 24576, r = idx - l * 24576, k = r / 96, n = r - k * 96;
    Wt_oa[l * 73728 + 192 * 256 + n * 256 + k] = f2bf(W_att[l * 24576 + r]);
    return;
  }
  idx -= 73728;
  if (idx < 196608) {  // W_out [3][256][256]
    int l = idx / 65536, r = idx - l * 65536, k = r >> 8, n = r & 255;
    Wt_out[l * 65536 + n * 256 + k] = f2bf(W_out[l * 65536 + r]);
    return;
  }
  idx -= 196608;
  if (idx < 393216) {  // W_ff1 [3][256][512]
    int l = idx / 131072, r = idx - l * 131072, k = r >> 9, n = r & 511;
    Wt_ff1[l * 131072 + n * 256 + k] = f2bf(W_ff1[l * 131072 + r]);
    return;
  }
  idx -= 393216;
  if (idx < 393216) {  // W_ff2 [3][512][256]
    int l = idx / 131072, r = idx - l * 131072, k = r >> 8, n = r & 255;
    Wt_ff2[l * 131072 + n * 512 + k] = f2bf(W_ff2[l * 131072 + r]);
    return;
  }
  idx -= 393216;
  if (idx < 524288) {  // deconv_w [oc][ic][8] -> [(tap*256+oc)][ic]
    int n = idx >> 8, k = idx & 255;
    Wt_dc[idx] = f2bf(deconv_w[(size_t)(n & 255) * 2048 + k * 8 + (n >> 8)]);
    return;
  }
  idx -= 524288;
  if (idx < 1327104) {  // conv3 per-fragment pack
    int tap = idx / 49152;
    int rem = idx - tap * 49152;
    int oc = rem >> 8, ic = rem & 255;
    int chunk = ic >> 5, kg = (ic >> 3) & 3, j = ic & 7;
    int ocblk = oc >> 4, lo = oc & 15;
    size_t frag = (size_t)(tap * 8 + chunk) * 12 + ocblk;
    wc3[(frag * 64 + kg * 16 + lo) * 8 + j] = f2bf(conv3_w[(oc * 256 + ic) * 27 + tap]);
    return;
  }
}

__global__ void k_cvt(const float* __restrict__ in, unsigned short* __restrict__ out, int n) {
  int i = blockIdx.x * 256 + threadIdx.x;
  if (i < n) out[i] = f2bf(in[i]);
}

// ---------------- restore: writes cam_x output (f32) AND bf16 GEMM-A layout ----------------
__global__ void k_restore2(const float* __restrict__ cx, const int* __restrict__ ids,
                           const float* __restrict__ mtok, float* __restrict__ out_camx,
                           unsigned short* __restrict__ camxT) {
  int idx = blockIdx.x * 256 + threadIdx.x;      // 811008, ch fastest
  if (idx >= 811008) return;
  int ch = idx % 768;
  int row = idx / 768;                           // c*176 + p
  int c = row / 176, p = row - c * 176;
  int id = ids[c * 176 + p];
  float v = (id < 44) ? cx[((size_t)(c * 44 + id)) * 768 + ch] : mtok[ch];
  camxT[idx] = f2bf(v);
  out_camx[((size_t)(c * 768 + ch)) * 176 + p] = v;
}

// ---------------- bf16 MFMA GEMM, B pre-transposed [N][K] bf16 ----------------
// MODE 0: f32 out Cf; MODE 2: bf16 out Cb; MODE 4: bf16 out + camera/level embeds
template <int MODE>
__global__ __launch_bounds__(256) void k_gemm(
    const unsigned short* __restrict__ A, int M, int lda,
    const unsigned short* __restrict__ Bt, int K, int N,
    const float* __restrict__ bias, const float* __restrict__ bias2, int n1, int relu,
    float* __restrict__ Cf, unsigned short* __restrict__ Cb, int ldc,
    const float* __restrict__ cemb, const float* __restrict__ lemb) {
  __shared__ short sA[128 * 40];
  const int t = threadIdx.x;
  const int l = t & 63, w = t >> 6;
  const int lo = l & 15, kg = l >> 4;
  const int row0 = blockIdx.x * 128, n0 = blockIdx.y * 64;
  const s16x8 bz = {0, 0, 0, 0, 0, 0, 0, 0};
  f32x4 acc[2][4] = {};
  s16x8 bc[4], bn[4];
#pragma unroll
  for (int nb = 0; nb < 4; ++nb) {
    int n = n0 + nb * 16 + lo;
    bc[nb] = (n < N) ? *(const s16x8*)&Bt[(size_t)n * K + kg * 8] : bz;
  }
  const int stR = t >> 1, stH = t & 1;
  for (int kc = 0; kc < K; kc += 32) {
    const bool pf = (kc + 32 < K);
    if (pf) {
#pragma unroll
      for (int nb = 0; nb < 4; ++nb) {
        int n = n0 + nb * 16 + lo;
        bn[nb] = (n < N) ? *(const s16x8*)&Bt[(size_t)n * K + kc + 32 + kg * 8] : bz;
      }
    }
    __syncthreads();
    {
      int r = row0 + stR;
      uint4 v0 = {0u, 0u, 0u, 0u}, v1 = {0u, 0u, 0u, 0u};
      if (r < M) {
        const unsigned short* src = A + (size_t)r * lda + kc + stH * 16;
        v0 = *(const uint4*)src;
        v1 = *(const uint4*)(src + 8);
      }
      *(uint4*)&sA[stR * 40 + stH * 16] = v0;
      *(uint4*)&sA[stR * 40 + stH * 16 + 8] = v1;
    }
    __syncthreads();
    s16x8 a0 = *(const s16x8*)&sA[(w * 32 + lo) * 40 + kg * 8];
    s16x8 a1 = *(const s16x8*)&sA[(w * 32 + 16 + lo) * 40 + kg * 8];
#pragma unroll
    for (int nb = 0; nb < 4; ++nb) {
      acc[0][nb] = __builtin_amdgcn_mfma_f32_16x16x32_bf16(a0, bc[nb], acc[0][nb], 0, 0, 0);
      acc[1][nb] = __builtin_amdgcn_mfma_f32_16x16x32_bf16(a1, bc[nb], acc[1][nb], 0, 0, 0);
    }
    if (pf) {
#pragma unroll
      for (int nb = 0; nb < 4; ++nb) bc[nb] = bn[nb];
    }
  }
#pragma unroll
  for (int m = 0; m < 2; ++m)
#pragma unroll
    for (int nb = 0; nb < 4; ++nb)
#pragma unroll
      for (int r = 0; r < 4; ++r) {
        int row = row0 + w * 32 + m * 16 + (kg << 2) + r;
        int col = n0 + nb * 16 + lo;
        if (row < M && col < N) {
          float v = acc[m][nb][r];
          if (bias) v += (col < n1) ? bias[col] : bias2[col - n1];
          if (relu) v = fmaxf(v, 0.f);
          if (MODE == 0) {
            Cf[(size_t)row * ldc + col] = v;
          } else if (MODE == 2) {
            Cb[(size_t)row * ldc + col] = f2bf(v);
          } else {  // MODE 4: vf epilogue — add camera + level embeds
            v += cemb[(row / 176) * 256 + col] + lemb[col];
            Cb[(size_t)row * ldc + col] = f2bf(v);
          }
        }
      }
}

// ---------------- deconv: A staged ONCE in 64KB LDS, all 32 col-tiles in-kernel ----------------
__global__ __launch_bounds__(256, 2) void k_deconv(const unsigned short* __restrict__ A,
                                                   const unsigned short* __restrict__ Bt,
                                                   unsigned short* __restrict__ Cb, int M) {
  __shared__ short sA[128 * 256];   // 64 KB, XOR-swizzled granules
  const int t = threadIdx.x;
  const int l = t & 63, w = t >> 6;
  const int lo = l & 15, kg = l >> 4;
  const int row0 = blockIdx.x * 128;
#pragma unroll
  for (int i = 0; i < 16; ++i) {    // 4096 granules of 16B
    int g = t + i * 256;
    int row = g >> 5, gcol = g & 31;
    int r = row0 + row;
    uint4 v = {0u, 0u, 0u, 0u};
    if (r < M) v = *(const uint4*)&A[(size_t)r * 256 + gcol * 8];
    *(uint4*)&sA[row * 256 + ((gcol ^ (row & 7)) << 3)] = v;
  }
  __syncthreads();
  const int r0 = w * 32 + lo, r1 = r0 + 16;
  for (int nt = 0; nt < 32; ++nt) {
    f32x4 acc[2][4] = {};
    s16x8 bc[4], bn[4];
    const int ncol0 = nt * 64;
#pragma unroll
    for (int nb = 0; nb < 4; ++nb)
      bc[nb] = *(const s16x8*)&Bt[(size_t)(ncol0 + nb * 16 + lo) * 256 + kg * 8];
#pragma unroll
    for (int kc = 0; kc < 8; ++kc) {
      const bool pf = kc < 7;
      if (pf) {
#pragma unroll
        for (int nb = 0; nb < 4; ++nb)
          bn[nb] = *(const s16x8*)&Bt[(size_t)(ncol0 + nb * 16 + lo) * 256 + (kc + 1) * 32 + kg * 8];
      }
      int g0 = kc * 4 + kg;
      s16x8 a0 = *(const s16x8*)&sA[r0 * 256 + ((g0 ^ (r0 & 7)) << 3)];
      s16x8 a1 = *(const s16x8*)&sA[r1 * 256 + ((g0 ^ (r1 & 7)) << 3)];
#pragma unroll
      for (int nb = 0; nb < 4; ++nb) {
        acc[0][nb] = __builtin_amdgcn_mfma_f32_16x16x32_bf16(a0, bc[nb], acc[0][nb], 0, 0, 0);
        acc[1][nb] = __builtin_amdgcn_mfma_f32_16x16x32_bf16(a1, bc[nb], acc[1][nb], 0, 0, 0);
      }
      if (pf) {
#pragma unroll
        for (int nb = 0; nb < 4; ++nb) bc[nb] = bn[nb];
      }
    }
    const int tap = nt >> 2;
    const int t1 = tap >> 2, t2 = (tap >> 1) & 1, t3 = tap & 1;
#pragma unroll
    for (int m = 0; m < 2; ++m)
#pragma unroll
      for (int nb = 0; nb < 4; ++nb)
#pragma unroll
        for (int r = 0; r < 4; ++r) {
          int row = row0 + w * 32 + m * 16 + (kg << 2) + r;
          if (row < M) {
            int oc = (nt & 3) * 64 + nb * 16 + lo;
            int z = row / 2500, rr = row - z * 2500;
            int hy = rr / 50, wx = rr - hy * 50;
            int od = 2 * wx + 1 - t1, oh = 2 * hy + 1 - t2, ow = 2 * z + 1 - t3;
            Cb[((size_t)((od * 100 + oh) * 16 + ow)) * 256 + oc] = f2bf(acc[m][nb][r]);
          }
        }
  }
}

// ---------------- softmax + bilinear sampling + aggregate, 8 queries/block ----------------
__global__ __launch_bounds__(256) void k_sample(const float* __restrict__ oa,
                                                const float* __restrict__ val,
                                                unsigned short* __restrict__ aggb) {
  __shared__ float sl[96], sw[96];
  int t = threadIdx.x;
  int h = t >> 5, d = t & 31;
  const float* vbh0 = val + (size_t)h * 32 + d;
  for (int r = 0; r < 8; ++r) {
    int n = blockIdx.x * 8 + r;
    if (t < 96) sl[t] = oa[(size_t)n * 288 + 192 + t];
    __syncthreads();
    if (t < 96) {
      int hh = t / 12;
      float mx = -1e30f;
#pragma unroll
      for (int j = 0; j < 12; ++j) mx = fmaxf(mx, sl[hh * 12 + j]);
      sw[t] = __expf(sl[t] - mx);
    }
    __syncthreads();
    float ssum = 0.f;
#pragma unroll
    for (int j = 0; j < 12; ++j) ssum += sw[h * 12 + j];
    float inv = 1.f / ssum;
    float xr = ((float)(n % 50) + 0.5f) * (22.0f / 50.0f) - 0.5f;
    float yr = ((float)((n / 50) % 50) + 0.5f) * (8.0f / 50.0f) - 0.5f;
    float acc = 0.f;
    const float* offn = oa + (size_t)n * 288 + h * 24;
#pragma unroll
    for (int c = 0; c < 6; ++c)
#pragma unroll
      for (int p2 = 0; p2 < 2; ++p2) {
        float x = xr + offn[(c * 2 + p2) * 2];
        float y = yr + offn[(c * 2 + p2) * 2 + 1];
        float x0 = floorf(x), y0 = floorf(y);
        float wx = x - x0, wy = y - y0;
        int ix0 = min(max((int)x0, 0), 21), ix1 = min(max((int)x0 + 1, 0), 21);
        int iy0 = min(max((int)y0, 0), 7), iy1 = min(max((int)y0 + 1, 0), 7);
        const float* vb = vbh0 + (size_t)c * 176 * 768;
        float v00 = vb[(size_t)(iy0 * 22 + ix0) * 768];
        float v01 = vb[(size_t)(iy0 * 22 + ix1) * 768];
        float v10 = vb[(size_t)(iy1 * 22 + ix0) * 768];
        float v11 = vb[(size_t)(iy1 * 22 + ix1) * 768];
        float bil = (1.f - wx) * (1.f - wy) * v00 + wx * (1.f - wy) * v01 +
                    (1.f - wx) * wy * v10 + wx * wy * v11;
        acc += sw[h * 12 + c * 2 + p2] * inv * bil;
      }
    aggb[(size_t)n * 256 + t] = f2bf(acc);
    __syncthreads();
  }
}

// ---------------- residual + LayerNorm(256), all-bf16 in/out, 8 rows/block ----------------
__global__ __launch_bounds__(256) void k_addln(unsigned short* __restrict__ qb,
                                               const unsigned short* __restrict__ p,
                                               const float* __restrict__ g, const float* __restrict__ b) {
  __shared__ float red[8];
  int t = threadIdx.x;
  int w = t >> 6;
  float gg = g[t], bb = b[t];
  for (int r = 0; r < 8; ++r) {
    size_t n = (size_t)blockIdx.x * 8 + r;
    float x = bf2f(qb[n * 256 + t]) + bf2f(p[n * 256 + t]);
    float s1 = x, s2 = x * x;
#pragma unroll
    for (int o = 32; o >= 1; o >>= 1) {
      s1 += __shfl_xor(s1, o, 64);
      s2 += __shfl_xor(s2, o, 64);
    }
    if ((t & 63) == 0) { red[w * 2] = s1; red[w * 2 + 1] = s2; }
    __syncthreads();
    s1 = red[0] + red[2] + red[4] + red[6];
    s2 = red[1] + red[3] + red[5] + red[7];
    float mean = s1 * (1.0f / 256.0f);
    float var = s2 * (1.0f / 256.0f) - mean * mean;
    float y = (x - mean) * rsqrtf(var + 1e-5f) * gg + bb;
    qb[n * 256 + t] = f2bf(y);
    __syncthreads();
  }
}

// ---------------- GroupNorm 1 (256 ch, 16 groups) ----------------
__global__ __launch_bounds__(256) void k_gnstat1(const unsigned short* __restrict__ X, float* __restrict__ part) {
  __shared__ float s1[256], s2[256];
  int b = blockIdx.x, t = threadIdx.x;
  int oc8 = t & 31, v0 = t >> 5;
  float a = 0.f, q = 0.f;
#pragma unroll
  for (int i = 0; i < 8; ++i) {
    int vox = v0 + i * 8;
    uint4 u = *(const uint4*)&X[(size_t)b * 16384 + vox * 256 + oc8 * 8];
    sum8(u, a, q);
  }
  s1[t] = a; s2[t] = q;
  __syncthreads();
  if (t < 128) { s1[t] += s1[t + 128]; s2[t] += s2[t + 128]; }
  __syncthreads();
  if (t < 64) { s1[t] += s1[t + 64]; s2[t] += s2[t + 64]; }
  __syncthreads();
  if (t < 32) { s1[t] += s1[t + 32]; s2[t] += s2[t + 32]; }
  __syncthreads();
  if (t < 16) {
    part[t * 2500 + b] = s1[2 * t] + s1[2 * t + 1];
    part[40000 + t * 2500 + b] = s2[2 * t] + s2[2 * t + 1];
  }
}

__global__ __launch_bounds__(256) void k_gnred1(const float* __restrict__ part, float* __restrict__ gmv) {
  __shared__ float s1[256], s2[256];
  int g = blockIdx.x, t = threadIdx.x;
  float a = 0.f, q = 0.f;
  for (int i = t; i < 2500; i += 256) { a += part[g * 2500 + i]; q += part[40000 + g * 2500 + i]; }
  s1[t] = a; s2[t] = q;
  __syncthreads();
  for (int s = 128; s > 0; s >>= 1) {
    if (t < s) { s1[t] += s1[t + s]; s2[t] += s2[t + s]; }
    __syncthreads();
  }
  if (t == 0) {
    float m = s1[0] / 2560000.0f;
    float v = s2[0] / 2560000.0f - m * m;
    gmv[2 * g] = m; gmv[2 * g + 1] = rsqrtf(v + 1e-5f);
  }
}

__global__ __launch_bounds__(256) void k_gnapply1(unsigned short* __restrict__ X, const float* __restrict__ gmv,
                                                  const float* __restrict__ g, const float* __restrict__ b) {
  for (unsigned i = blockIdx.x * 256 + threadIdx.x; i < 5120000u; i += gridDim.x * 256) {
    unsigned e = i * 8u;
    int oc0 = e & 255, grp = oc0 >> 4;
    float mean = gmv[grp * 2], rstd = gmv[grp * 2 + 1];
    float4 g0 = *(const float4*)&g[oc0], g1 = *(const float4*)&g[oc0 + 4];
    float4 b0 = *(const float4*)&b[oc0], b1 = *(const float4*)&b[oc0 + 4];
    uint4 u = *(const uint4*)&X[e];
    unsigned w[4] = {u.x, u.y, u.z, u.w};
    float gg[8] = {g0.x, g0.y, g0.z, g0.w, g1.x, g1.y, g1.z, g1.w};
    float bb[8] = {b0.x, b0.y, b0.z, b0.w, b1.x, b1.y, b1.z, b1.w};
    unsigned o[4];
#pragma unroll
    for (int j = 0; j < 4; ++j) {
      float v0 = __uint_as_float((w[j] & 0xFFFFu) << 16);
      float v1 = __uint_as_float(w[j] & 0xFFFF0000u);
      v0 = fmaxf((v0 - mean) * rstd * gg[2 * j] + bb[2 * j], 0.f);
      v1 = fmaxf((v1 - mean) * rstd * gg[2 * j + 1] + bb[2 * j + 1], 0.f);
      o[j] = (unsigned)f2bf(v0) | ((unsigned)f2bf(v1) << 16);
    }
    *(uint4*)&X[e] = make_uint4(o[0], o[1], o[2], o[3]);
  }
}

// ---------------- conv3 3x3x3 (256->192): round-6 structure (measured best, untouched) ----------------
__global__ __launch_bounds__(256, 2) void k_conv3(const unsigned short* __restrict__ X,
                                                  const unsigned short* __restrict__ Wp,
                                                  unsigned short* __restrict__ Y) {
  __shared__ short sX[4 * 543 * 8];    // 34.75 KB
  int bid = blockIdx.x;
  int xcd = bid & 7, idx = bid >> 3;
  int swz = (xcd < 4 ? xcd * 163 : 652 + (xcd - 4) * 162) + idx;
  const int od = swz / 13;
  const int oh0 = (swz - od * 13) * 8;
  const int t = threadIdx.x;
  const int l = t & 63, w = t >> 6;
  const int kg = l >> 4, lo = l & 15;
  f32x4 acc[8][3] = {};
  s16x8 bc[9], bn[9];
  const unsigned short* Wl = Wp + (size_t)l * 8;
  const int w3 = w * 3;
#pragma unroll
  for (int t2 = 0; t2 < 3; ++t2)
#pragma unroll
    for (int nb = 0; nb < 3; ++nb)
      bc[t2 * 3 + nb] = *(const s16x8*)&Wl[(size_t)((t2 * 3 * 8) * 12 + w3 + nb) * 512];

  for (int gi = 0; gi < 72; ++gi) {
    const int chunk = gi / 9;
    const int sub = gi - chunk * 9;
    const int t1 = sub / 3, t3 = sub - t1 * 3;
    if (sub == 0) {
      __syncthreads();
#pragma unroll
      for (int i = 0; i < 9; ++i) {   // stage slab: 540 pos x 4 kgrp uint4
        int e = t + i * 256;
        if (e < 2160) {
          int pos = e >> 2, ks = e & 3;
          int sd = pos / 180, r2 = pos - sd * 180;
          int sh = r2 / 18, sw_ = r2 - sh * 18;
          int gd = od + sd - 1, gh = oh0 + sh - 1, gw = sw_ - 1;
          uint4 v = {0u, 0u, 0u, 0u};
          if ((unsigned)gd < 100u && (unsigned)gh < 100u && (unsigned)gw < 16u)
            v = *(const uint4*)&X[((size_t)((gd * 100 + gh) * 16 + gw)) * 256 + chunk * 32 + ks * 8];
          *(uint4*)&sX[(ks * 543 + pos) * 8] = v;
        }
      }
      __syncthreads();
    }
    const int gn1 = gi + 1;
    if (gn1 < 72) {
      const int c1 = gn1 / 9, su1 = gn1 - c1 * 9;
      const int t1n = su1 / 3, t3n = su1 - t1n * 3;
#pragma unroll
      for (int t2 = 0; t2 < 3; ++t2)
#pragma unroll
        for (int nb = 0; nb < 3; ++nb)
          bn[t2 * 3 + nb] = *(const s16x8*)&Wl[
              (size_t)(((t1n * 9 + t2 * 3 + t3n) * 8 + c1) * 12 + w3 + nb) * 512];
    }
    const int abase = kg * 543 + t1 * 180 + lo + t3;
#pragma unroll
    for (int sh = 0; sh < 10; ++sh) {
      s16x8 a = *(const s16x8*)&sX[(abase + sh * 18) * 8];
#pragma unroll
      for (int t2 = 0; t2 < 3; ++t2) {
        const int m = sh - t2;
        if (m >= 0 && m < 8) {
          acc[m][0] = __builtin_amdgcn_mfma_f32_16x16x32_bf16(a, bc[t2 * 3 + 0], acc[m][0], 0, 0, 0);
          acc[m][1] = __builtin_amdgcn_mfma_f32_16x16x32_bf16(a, bc[t2 * 3 + 1], acc[m][1], 0, 0, 0);
          acc[m][2] = __builtin_amdgcn_mfma_f32_16x16x32_bf16(a, bc[t2 * 3 + 2], acc[m][2], 0, 0, 0);
        }
      }
    }
#pragma unroll
    for (int i = 0; i < 9; ++i) bc[i] = bn[i];
  }
#pragma unroll
  for (int m = 0; m < 8; ++m) {
    int oh = oh0 + m;
    if (oh < 100) {
#pragma unroll
      for (int nb = 0; nb < 3; ++nb)
#pragma unroll
        for (int r = 0; r < 4; ++r) {
          int oc = w * 48 + nb * 16 + lo;
          int ow = (kg << 2) + r;
          Y[(size_t)oc * 160000 + (size_t)((od * 100 + oh) * 16) + ow] = f2bf(acc[m][nb][r]);
        }
    }
  }
}

// ---------------- GroupNorm 2 ----------------
__global__ __launch_bounds__(256) void k_gnstat2(const unsigned short* __restrict__ X, float* __restrict__ part) {
  __shared__ float s1[256], s2[256];
  int b = blockIdx.x, t = threadIdx.x;
  int ch = b / 10, pp = b - ch * 10;
  const unsigned short* base = X + (size_t)ch * 160000 + (size_t)pp * 16000;
  float a = 0.f, q = 0.f;
  for (int i = t; i < 2000; i += 256) {
    uint4 u = *(const uint4*)&base[i * 8];
    sum8(u, a, q);
  }
  s1[t] = a; s2[t] = q;
  __syncthreads();
  for (int s = 128; s > 0; s >>= 1) {
    if (t < s) { s1[t] += s1[t + s]; s2[t] += s2[t + s]; }
    __syncthreads();
  }
  if (t == 0) { part[80000 + ch * 10 + pp] = s1[0]; part[81920 + ch * 10 + pp] = s2[0]; }
}

__global__ __launch_bounds__(256) void k_gnred2(const float* __restrict__ part, float* __restrict__ gmv) {
  __shared__ float s1[256], s2[256];
  int g = blockIdx.x, t = threadIdx.x;
  float a = (t < 120) ? part[80000 + g * 120 + t] : 0.f;
  float q = (t < 120) ? part[81920 + g * 120 + t] : 0.f;
  s1[t] = a; s2[t] = q;
  __syncthreads();
  for (int s = 128; s > 0; s >>= 1) {
    if (t < s) { s1[t] += s1[t + s]; s2[t] += s2[t + s]; }
    __syncthreads();
  }
  if (t == 0) {
    float m = s1[0] / 1920000.0f;
    float v = s2[0] / 1920000.0f - m * m;
    gmv[2 * g] = m; gmv[2 * g + 1] = rsqrtf(v + 1e-5f);
  }
}

__global__ __launch_bounds__(256) void k_gnapply2(const unsigned short* __restrict__ X, const float* __restrict__ gmv,
                                                  const float* __restrict__ g, const float* __restrict__ b,
                                                  float* __restrict__ out) {
  for (unsigned i = blockIdx.x * 256 + threadIdx.x; i < 3840000u; i += gridDim.x * 256) {
    unsigned oc = i / 20000u;
    unsigned grp = oc / 12u;
    float mean = gmv[grp * 2], rstd = gmv[grp * 2 + 1];
    float gam = g[oc], bet = b[oc];
    unsigned e = i * 8u;
    uint4 u = *(const uint4*)&X[e];
    unsigned wv[4] = {u.x, u.y, u.z, u.w};
    float o[8];
#pragma unroll
    for (int j = 0; j < 4; ++j) {
      float v0 = __uint_as_float((wv[j] & 0xFFFFu) << 16);
      float v1 = __uint_as_float(wv[j] & 0xFFFF0000u);
      o[2 * j] = fmaxf((v0 - mean) * rstd * gam + bet, 0.f);
      o[2 * j + 1] = fmaxf((v1 - mean) * rstd * gam + bet, 0.f);
    }
    *(float4*)&out[e] = make_float4(o[0], o[1], o[2], o[3]);
    *(float4*)&out[e + 4] = make_float4(o[4], o[5], o[6], o[7]);
  }
}

// ---------------- host ----------------
static inline dim3 gemm_grid(int M, int N) { return dim3((M + 127) / 128, (N + 63) / 64); }

extern "C" void kernel_launch(void* const* d_in, const int* in_sizes, int n_in,
                              void* d_out, int out_size, void* d_ws, size_t ws_size,
                              hipStream_t stream) {
  const float* camera_x = (const float*)d_in[0];
  const int* ids = (const int*)d_in[1];
  const float* mask_tok = (const float*)d_in[4];
  const float* vol_emb = (const float*)d_in[5];
  const float* W_tc = (const float*)d_in[6];
  const float* b_tc = (const float*)d_in[7];
  const float* cams_emb = (const float*)d_in[8];
  const float* lvl_emb = (const float*)d_in[9];
  const float* W_off = (const float*)d_in[10];
  const float* b_off = (const float*)d_in[11];
  const float* W_att = (const float*)d_in[12];
  const float* b_att = (const float*)d_in[13];
  const float* W_val = (const float*)d_in[14];
  const float* b_val = (const float*)d_in[15];
  const float* W_out = (const float*)d_in[16];
  const float* b_out = (const float*)d_in[17];
  const float* ln1_g = (const float*)d_in[18];
  const float* ln1_b = (const float*)d_in[19];
  const float* W_ff1 = (const float*)d_in[20];
  const float* b_ff1 = (const float*)d_in[21];
  const float* W_ff2 = (const float*)d_in[22];
  const float* b_ff2 = (const float*)d_in[23];
  const float* ln2_g = (const float*)d_in[24];
  const float* ln2_b = (const float*)d_in[25];
  const float* deconv_w = (const float*)d_in[26];
  const float* gn1_g = (const float*)d_in[27];
  const float* gn1_b = (const float*)d_in[28];
  const float* conv3_w = (const float*)d_in[29];
  const float* gn2_g = (const float*)d_in[30];
  const float* gn2_b = (const float*)d_in[31];

  char* ws = (char*)d_ws;
  unsigned short* qb   = (unsigned short*)(ws + 20480000);      // 10.24 MB
  unsigned short* projb= (unsigned short*)(ws + 30720000);      // 10.24 MB (bf16 now)
  float* oa            = (float*)(ws + 51200000);               // 23.04 MB
  unsigned short* aggb = (unsigned short*)(ws + 74240000);      // 10.24 MB
  unsigned short* ffhb = (unsigned short*)(ws + 84480000);      // 20.48 MB
  float* val3          = (float*)(ws + 104960000);              // 3.24 MB [1056][768]
  unsigned short* featb= (unsigned short*)(ws + 108204032);     // 0.54 MB
  unsigned short* x1bf = (unsigned short*)(ws + 30720000);      // 81.92 MB (aliases decoder scratch)
  unsigned short* c3   = (unsigned short*)(ws + 112640000);     // 61.44 MB
  unsigned short* Wt_val = (unsigned short*)(ws + 174080000);
  unsigned short* Wt_oa  = (unsigned short*)(ws + 174473216);
  unsigned short* Wt_out = (unsigned short*)(ws + 174915584);
  unsigned short* Wt_ff1 = (unsigned short*)(ws + 175308800);
  unsigned short* Wt_ff2 = (unsigned short*)(ws + 176095232);
  unsigned short* Wt_dc  = (unsigned short*)(ws + 176881664);
  unsigned short* wc3    = (unsigned short*)(ws + 177930240);
  float* part = (float*)(ws + 180584448);
  float* gmv1 = (float*)(ws + 180920320);
  float* gmv2 = (float*)(ws + 180920448);
  unsigned short* Wt_tc  = (unsigned short*)(ws + 180920576);   // 393216 B
  unsigned short* camxT  = (unsigned short*)(ws + 181707008);   // 1622016 B

  float* out_x = (float*)d_out;
  float* out_camx = out_x + 30720000;

  // all weight prep in ONE launch (3,448,832 elements)
  k_prep<<<13472, 256, 0, stream>>>(W_tc, W_val, W_off, W_att, W_out, W_ff1, W_ff2,
                                    deconv_w, conv3_w,
                                    Wt_tc, Wt_val, Wt_oa, Wt_out, Wt_ff1, Wt_ff2, Wt_dc, wc3);

  k_restore2<<<3168, 256, 0, stream>>>(camera_x, ids, mask_tok, out_camx, camxT);
  // vf = relu(camxT @ W_tc^T + b_tc) + cams/level embeds (mode 4)
  k_gemm<4><<<gemm_grid(1056, 256), 256, 0, stream>>>(camxT, 1056, 768, Wt_tc, 768, 256,
                                                      b_tc, nullptr, 256, 1, nullptr, featb, 256,
                                                      cams_emb, lvl_emb);
  k_cvt<<<20000, 256, 0, stream>>>(vol_emb, qb, 5120000);

  // val for ALL 3 layers in one GEMM: [1056][768], bias = flat b_val
  k_gemm<0><<<gemm_grid(1056, 768), 256, 0, stream>>>(featb, 1056, 256, Wt_val, 256, 768,
                                                      b_val, nullptr, 768, 0, val3, nullptr, 768,
                                                      nullptr, nullptr);

  for (int lyr = 0; lyr < 3; ++lyr) {
    k_gemm<0><<<gemm_grid(20000, 288), 256, 0, stream>>>(qb, 20000, 256, Wt_oa + lyr * 73728, 256, 288,
                                                         b_off + lyr * 192, b_att + lyr * 96, 192, 0,
                                                         oa, nullptr, 288, nullptr, nullptr);
    k_sample<<<2500, 256, 0, stream>>>(oa, val3 + lyr * 256, aggb);
    k_gemm<2><<<gemm_grid(20000, 256), 256, 0, stream>>>(aggb, 20000, 256, Wt_out + lyr * 65536, 256, 256,
                                                         b_out + lyr * 256, nullptr, 256, 0,
                                                         nullptr, projb, 256, nullptr, nullptr);
    k_addln<<<2500, 256, 0, stream>>>(qb, projb, ln1_g + lyr * 256, ln1_b + lyr * 256);
    k_gemm<2><<<gemm_grid(20000, 512), 256, 0, stream>>>(qb, 20000, 256, Wt_ff1 + lyr * 131072, 256, 512,
                                                         b_ff1 + lyr * 512, nullptr, 512, 1,
                                                         nullptr, ffhb, 512, nullptr, nullptr);
    k_gemm<2><<<gemm_grid(20000, 256), 256, 0, stream>>>(ffhb, 20000, 512, Wt_ff2 + lyr * 131072, 512, 256,
                                                         b_ff2 + lyr * 256, nullptr, 256, 0,
                                                         nullptr, projb, 256, nullptr, nullptr);
    k_addln<<<2500, 256, 0, stream>>>(qb, projb, ln2_g + lyr * 256, ln2_b + lyr * 256);
  }

  // deconv: A staged once, all 8 taps in-kernel
  k_deconv<<<157, 256, 0, stream>>>(qb, Wt_dc, x1bf, 20000);

  k_gnstat1<<<2500, 256, 0, stream>>>(x1bf, part);
  k_gnred1<<<16, 256, 0, stream>>>(part, gmv1);
  k_gnapply1<<<2048, 256, 0, stream>>>(x1bf, gmv1, gn1_g, gn1_b);

  k_conv3<<<1300, 256, 0, stream>>>(x1bf, wc3, c3);

  k_gnstat2<<<1920, 256, 0, stream>>>(c3, part);
  k_gnred2<<<16, 256, 0, stream>>>(part, gmv2);
  k_gnapply2<<<2048, 256, 0, stream>>>(c3, gmv2, gn2_g, gn2_b, out_x);
}